// Round 11
// baseline (2553.409 us; speedup 1.0000x reference)
//
#include <hip/hip_runtime.h>

#define N_SURF 30000
#define N_GRAPH 12000
#define K_EIG 128
#define HID 64
#define E_GRAPH 192000

static inline int cdiv(int a, int b) { return (a + b - 1) / b; }

// ---------------------------------------------------------------- small utils
__global__ void k_fill(float* __restrict__ p, float v, int n) {
    int t = blockIdx.x * blockDim.x + threadIdx.x;
    if (t < n) p[t] = v;
}

__global__ void k_to_dinv(float* __restrict__ p, int n) {
    int t = blockIdx.x * blockDim.x + threadIdx.x;
    if (t < n) p[t] = 1.0f / sqrtf(p[t]);
}

// deg accumulation (indices arrive as int32 from the harness)
__global__ void k_deg_graph(const int* __restrict__ gdst, float* __restrict__ deg, int E) {
    int t = blockIdx.x * blockDim.x + threadIdx.x;
    if (t < E) atomicAdd(&deg[gdst[t]], 1.0f);
}

__global__ void k_deg_bi(const int* __restrict__ bs, const int* __restrict__ bg,
                         const float* __restrict__ w, float* __restrict__ deg_s,
                         float* __restrict__ deg_g, int E) {
    int t = blockIdx.x * blockDim.x + threadIdx.x;
    if (t < E) {
        float wv = w[t];
        atomicAdd(&deg_s[bs[t]], wv);
        atomicAdd(&deg_g[bg[t] - N_SURF], wv);
    }
}

__global__ void k_prep_graph(const int* __restrict__ ei, const float* __restrict__ dinv,
                             float* __restrict__ norm, int E) {
    int t = blockIdx.x * blockDim.x + threadIdx.x;
    if (t < E) {
        int s = ei[t], d = ei[E + t];
        norm[t] = dinv[s] * dinv[d];
    }
}

__global__ void k_prep_bi(const int* __restrict__ bs64, const int* __restrict__ bg64,
                          const float* __restrict__ w, const float* __restrict__ dinv_s,
                          const float* __restrict__ dinv_g, int* __restrict__ bg32,
                          float* __restrict__ norm_gs, float* __restrict__ norm_sg, int E) {
    int t = blockIdx.x * blockDim.x + threadIdx.x;
    if (t < E) {
        int s = bs64[t];
        int g = bg64[t] - N_SURF;
        bg32[t] = g;
        float wv = w[t];
        norm_gs[t] = dinv_s[s] * wv;   // gs conv: src graph (dinv=1), dst surf
        norm_sg[t] = dinv_g[g] * wv;   // sg conv: src surf (dinv=1), dst graph
    }
}

// ---------------------------------------------------------------- input linears
__global__ void k_lin(const float* __restrict__ X, const float* __restrict__ W,
                      const float* __restrict__ b, float* __restrict__ out, int M, int K) {
    int t = blockIdx.x * blockDim.x + threadIdx.x;
    if (t >= M * HID) return;
    int r = t >> 6, h = t & 63;
    float acc = b[h];
    for (int k = 0; k < K; ++k) acc = fmaf(X[r * K + k], W[k * HID + h], acc);
    out[t] = acc;
}

// ---------------------------------------------------------------- spec = evecs^T @ (mass * dx)
__global__ __launch_bounds__(256) void k_spec(const float* __restrict__ evecs,
                                              const float* __restrict__ mass,
                                              const float* __restrict__ dx,
                                              float* __restrict__ spec) {
    __shared__ float evs[32 * 128];
    __shared__ float xms[32 * 64];
    const int h = threadIdx.x & 63, eg = threadIdx.x >> 6;
    float acc[32];
#pragma unroll
    for (int i = 0; i < 32; ++i) acc[i] = 0.f;
    for (int r0 = blockIdx.x * 32; r0 < N_SURF; r0 += gridDim.x * 32) {
        __syncthreads();
        for (int idx = threadIdx.x; idx < 32 * 128; idx += 256) {
            int rr = idx >> 7, k = idx & 127;
            int row = r0 + rr;
            evs[idx] = (row < N_SURF) ? evecs[(size_t)row * 128 + k] : 0.f;
        }
        for (int idx = threadIdx.x; idx < 32 * 64; idx += 256) {
            int rr = idx >> 6, c = idx & 63;
            int row = r0 + rr;
            xms[idx] = (row < N_SURF) ? mass[row] * dx[(size_t)row * 64 + c] : 0.f;
        }
        __syncthreads();
        for (int rr = 0; rr < 32; ++rr) {
            float xv = xms[rr * 64 + h];
            const float* ep = &evs[rr * 128 + eg * 32];
#pragma unroll
            for (int e = 0; e < 32; ++e) acc[e] = fmaf(ep[e], xv, acc[e]);
        }
    }
#pragma unroll
    for (int e = 0; e < 32; ++e) atomicAdd(&spec[(eg * 32 + e) * 64 + h], acc[e]);
}

// Bs[k][h] = exp(-evals[k] * max(t[h],1e-8)) * spec[k][h]
__global__ void k_bscale(const float* __restrict__ spec, const float* __restrict__ evals,
                         const float* __restrict__ t, float* __restrict__ Bs) {
    int idx = blockIdx.x * blockDim.x + threadIdx.x;
    if (idx >= 128 * 64) return;
    int k = idx >> 6, h = idx & 63;
    float tt = fmaxf(t[h], 1e-8f);
    Bs[idx] = expf(-evals[k] * tt) * spec[idx];
}

// ---------------------------------------------------------------- generic GEMM C[M x 64] = op(A[M x K]) @ B[K x 64]
template <int K, bool RELU_A>
__global__ __launch_bounds__(256) void k_gemm64(const float* __restrict__ A,
                                                const float* __restrict__ B,
                                                float* __restrict__ C, int M) {
    __shared__ float Bs[K * 64];
    __shared__ float As[64 * K];
    for (int idx = threadIdx.x; idx < K * 64; idx += 256) Bs[idx] = B[idx];
    const int h = threadIdx.x & 63, rg = threadIdx.x >> 6;
    for (int r0 = blockIdx.x * 64; r0 < M; r0 += gridDim.x * 64) {
        __syncthreads();
        for (int idx = threadIdx.x; idx < 64 * K; idx += 256) {
            int rr = idx / K, k = idx - rr * K;
            int row = r0 + rr;
            float v = (row < M) ? A[(size_t)row * K + k] : 0.f;
            if (RELU_A) v = fmaxf(v, 0.f);
            As[idx] = v;
        }
        __syncthreads();
        float acc[16];
#pragma unroll
        for (int i = 0; i < 16; ++i) acc[i] = 0.f;
        for (int k = 0; k < K; k += 4) {
            float b0 = Bs[(k + 0) * 64 + h], b1 = Bs[(k + 1) * 64 + h];
            float b2 = Bs[(k + 2) * 64 + h], b3 = Bs[(k + 3) * 64 + h];
#pragma unroll
            for (int i = 0; i < 16; ++i) {
                const float* ap = &As[(rg * 16 + i) * K + k];
                acc[i] = fmaf(ap[0], b0, fmaf(ap[1], b1, fmaf(ap[2], b2, fmaf(ap[3], b3, acc[i]))));
            }
        }
#pragma unroll
        for (int i = 0; i < 16; ++i) {
            int row = r0 + rg * 16 + i;
            if (row < M) C[(size_t)row * 64 + h] = acc[i];
        }
    }
}

// ---------------------------------------------------------------- fused 3-layer MLP (per-row), in-place residual on dx
__global__ __launch_bounds__(256) void k_mlp(float* __restrict__ dx, const float* __restrict__ xd,
                                             const float* __restrict__ w0, const float* __restrict__ b0,
                                             const float* __restrict__ w1, const float* __restrict__ b1,
                                             const float* __restrict__ w2, const float* __restrict__ b2,
                                             int M) {
    __shared__ float w0s[128 * 64];
    __shared__ float w1s[64 * 64];
    __shared__ float w2s[64 * 64];
    __shared__ float bsh[3][64];
    __shared__ float feat[4][128];
    __shared__ float h1s[4][64];
    __shared__ float h2s[4][64];
    for (int idx = threadIdx.x; idx < 8192; idx += 256) w0s[idx] = w0[idx];
    for (int idx = threadIdx.x; idx < 4096; idx += 256) { w1s[idx] = w1[idx]; w2s[idx] = w2[idx]; }
    if (threadIdx.x < 64) {
        bsh[0][threadIdx.x] = b0[threadIdx.x];
        bsh[1][threadIdx.x] = b1[threadIdx.x];
        bsh[2][threadIdx.x] = b2[threadIdx.x];
    }
    const int h = threadIdx.x & 63, rg = threadIdx.x >> 6;
    for (int r0 = blockIdx.x * 4; r0 < M; r0 += gridDim.x * 4) {
        int r = r0 + rg;
        __syncthreads();
        feat[rg][h] = dx[(size_t)r * 64 + h];
        feat[rg][64 + h] = xd[(size_t)r * 64 + h];
        __syncthreads();
        float acc = bsh[0][h];
        for (int k = 0; k < 128; k += 4) {
            const float* fp = &feat[rg][k];
            acc = fmaf(fp[0], w0s[(k + 0) * 64 + h],
                  fmaf(fp[1], w0s[(k + 1) * 64 + h],
                  fmaf(fp[2], w0s[(k + 2) * 64 + h],
                  fmaf(fp[3], w0s[(k + 3) * 64 + h], acc))));
        }
        h1s[rg][h] = fmaxf(acc, 0.f);
        __syncthreads();
        acc = bsh[1][h];
        for (int k = 0; k < 64; k += 4) {
            const float* fp = &h1s[rg][k];
            acc = fmaf(fp[0], w1s[(k + 0) * 64 + h],
                  fmaf(fp[1], w1s[(k + 1) * 64 + h],
                  fmaf(fp[2], w1s[(k + 2) * 64 + h],
                  fmaf(fp[3], w1s[(k + 3) * 64 + h], acc))));
        }
        h2s[rg][h] = fmaxf(acc, 0.f);
        __syncthreads();
        acc = bsh[2][h];
        for (int k = 0; k < 64; k += 4) {
            const float* fp = &h2s[rg][k];
            acc = fmaf(fp[0], w2s[(k + 0) * 64 + h],
                  fmaf(fp[1], w2s[(k + 1) * 64 + h],
                  fmaf(fp[2], w2s[(k + 2) * 64 + h],
                  fmaf(fp[3], w2s[(k + 3) * 64 + h], acc))));
        }
        dx[(size_t)r * 64 + h] += acc;
    }
}

// ---------------------------------------------------------------- conv init: out = dinv^2 * H + b
__global__ void k_conv_init64(float* __restrict__ out, const float* __restrict__ H,
                              const float* __restrict__ dinv, const float* __restrict__ b, int M) {
    int t = blockIdx.x * blockDim.x + threadIdx.x;
    if (t >= M * 64) return;
    int r = t >> 6, h = t & 63;
    float dv = dinv[r];
    out[t] = fmaf(dv * dv, H[t], b[h]);
}

__global__ void k_conv_init1(float* __restrict__ out, const float* __restrict__ H1,
                             const float* __restrict__ dinv, const float* __restrict__ b, int M) {
    int t = blockIdx.x * blockDim.x + threadIdx.x;
    if (t >= M) return;
    float dv = dinv[t];
    out[t] = fmaf(dv * dv, H1[t], b[0]);
}

// ---------------------------------------------------------------- scatters
__global__ void k_scatter(const int* __restrict__ src, const int* __restrict__ dst,
                          const float* __restrict__ norm, const float* __restrict__ H,
                          float* __restrict__ out, int E, int src_stride2, int dst_off) {
    int gid = blockIdx.x * blockDim.x + threadIdx.x;
    int e = gid >> 6;
    if (e >= E) return;
    int h = gid & 63;
    atomicAdd(&out[(size_t)(dst[e] - dst_off) * 64 + h],
              norm[e] * H[(size_t)src[e] * 64 + h]);
}

// run-length variant: accumulate consecutive equal-dst runs in registers
// (correct for ANY dst ordering — every edge is atomically added exactly once;
//  sortedness only reduces the atomic count)
__global__ void k_scatter_run(const int* __restrict__ src, const int* __restrict__ dst,
                              const float* __restrict__ norm, const float* __restrict__ H,
                              float* __restrict__ out, int E) {
    int gid = blockIdx.x * blockDim.x + threadIdx.x;
    int h = gid & 63;
    int chunk = gid >> 6;
    int e0 = chunk * 32;
    if (e0 >= E) return;
    int e1 = min(e0 + 32, E);
    int cur = dst[e0];
    float acc = 0.f;
    for (int e = e0; e < e1; ++e) {
        int d = dst[e];
        if (d != cur) { atomicAdd(&out[(size_t)cur * 64 + h], acc); acc = 0.f; cur = d; }
        acc = fmaf(norm[e], H[(size_t)src[e] * 64 + h], acc);
    }
    atomicAdd(&out[(size_t)cur * 64 + h], acc);
}

__global__ void k_scatter1(const int* __restrict__ src, const int* __restrict__ dst,
                           const float* __restrict__ norm, const float* __restrict__ H1,
                           float* __restrict__ out, int E) {
    int e = blockIdx.x * blockDim.x + threadIdx.x;
    if (e >= E) return;
    atomicAdd(&out[dst[e]], norm[e] * H1[src[e]]);
}

__global__ void k_scatter_run1(const int* __restrict__ src, const int* __restrict__ dst,
                               const float* __restrict__ norm, const float* __restrict__ H1,
                               float* __restrict__ out, int E) {
    int chunk = blockIdx.x * blockDim.x + threadIdx.x;
    int e0 = chunk * 32;
    if (e0 >= E) return;
    int e1 = min(e0 + 32, E);
    int cur = dst[e0];
    float acc = 0.f;
    for (int e = e0; e < e1; ++e) {
        int d = dst[e];
        if (d != cur) { atomicAdd(&out[cur], acc); acc = 0.f; cur = d; }
        acc = fmaf(norm[e], H1[src[e]], acc);
    }
    atomicAdd(&out[cur], acc);
}

// ---------------------------------------------------------------- GEMV (last block, HID -> 1)
__global__ void k_gemv64(const float* __restrict__ A, const float* __restrict__ w,
                         float* __restrict__ out, int M) {
    int gid = blockIdx.x * blockDim.x + threadIdx.x;
    int r = gid >> 6, l = gid & 63;
    if (r >= M) return;
    float v = A[(size_t)r * 64 + l] * w[l];
    for (int off = 32; off; off >>= 1) v += __shfl_down(v, off, 64);
    if (l == 0) out[r] = v;
}

// ================================================================ host
extern "C" void kernel_launch(void* const* d_in, const int* in_sizes, int n_in,
                              void* d_out, int out_size, void* d_ws, size_t ws_size,
                              hipStream_t stream) {
    const float* x_surf   = (const float*)d_in[0];
    const float* x_graph  = (const float*)d_in[1];
    const float* mass     = (const float*)d_in[2];
    const float* evals    = (const float*)d_in[3];
    const float* evecs    = (const float*)d_in[4];
    const float* bi_w     = (const float*)d_in[5];
    const float* lin1_w   = (const float*)d_in[6];
    const float* lin1_b   = (const float*)d_in[7];
    const float* lin2_w   = (const float*)d_in[8];
    const float* lin2_b   = (const float*)d_in[9];
    const float* diff_time= (const float*)d_in[10];
    const float* mlp_w0   = (const float*)d_in[11];
    const float* mlp_b0   = (const float*)d_in[12];
    const float* mlp_w1   = (const float*)d_in[13];
    const float* mlp_b1   = (const float*)d_in[14];
    const float* mlp_w2   = (const float*)d_in[15];
    const float* mlp_b2   = (const float*)d_in[16];
    const float* gcn_w1   = (const float*)d_in[17];
    const float* gcn_b1   = (const float*)d_in[18];
    const float* gcn_w2   = (const float*)d_in[19];
    const float* gcn_b2   = (const float*)d_in[20];
    const float* gs_w     = (const float*)d_in[21];
    const float* gs_b     = (const float*)d_in[22];
    const float* gs_w_last= (const float*)d_in[23];
    const float* gs_b_last= (const float*)d_in[24];
    const float* sg_w     = (const float*)d_in[25];
    const float* sg_b     = (const float*)d_in[26];
    const float* sg_w_last= (const float*)d_in[27];
    const float* sg_b_last= (const float*)d_in[28];
    const int* graph_ei   = (const int*)d_in[29];   // int32 from harness
    const int* bi_s       = (const int*)d_in[30];   // int32, values [0, N_SURF)
    const int* bi_g       = (const int*)d_in[31];   // int32, values [N_SURF, N_SURF+N_GRAPH)
    const int E = in_sizes[5];
    float* out = (float*)d_out;

    // ---- workspace carve (floats) — total ≈ 62 MB at E≈1.3M
    float* p = (float*)d_ws;
    float* surfA = p; p += (size_t)N_SURF * 64;
    float* surfB = p; p += (size_t)N_SURF * 64;
    float* xd    = p; p += (size_t)N_SURF * 64;
    float* hs    = p; p += (size_t)N_SURF * 64;
    float* gA    = p; p += (size_t)N_GRAPH * 64;
    float* gB    = p; p += (size_t)N_GRAPH * 64;
    float* tmpg  = p; p += (size_t)N_GRAPH * 64;
    float* hg    = p; p += (size_t)N_GRAPH * 64;
    float* spec  = p; p += 128 * 64;
    float* Bsc   = p; p += 128 * 64;
    float* dinv_s  = p; p += N_SURF;
    float* dinv_g  = p; p += N_GRAPH;
    float* dinv_gr = p; p += N_GRAPH;
    float* norm_gr = p; p += E_GRAPH;
    float* norm_gs = p; p += E;
    float* norm_sg = p; p += E;
    int* bg32 = (int*)p; p += E;

    float* dx  = surfA;
    float* nsx = surfB;
    float* gx  = gA;
    float* gx2 = gB;

    // ---- setup: input linears, degrees, norms
    k_lin<<<cdiv(N_SURF * 64, 256), 256, 0, stream>>>(x_surf, lin1_w, lin1_b, dx, N_SURF, 5);
    k_lin<<<cdiv(N_GRAPH * 64, 256), 256, 0, stream>>>(x_graph, lin2_w, lin2_b, gx, N_GRAPH, 20);
    k_fill<<<cdiv(N_SURF, 256), 256, 0, stream>>>(dinv_s, 1.f, N_SURF);
    k_fill<<<cdiv(N_GRAPH, 256), 256, 0, stream>>>(dinv_g, 1.f, N_GRAPH);
    k_fill<<<cdiv(N_GRAPH, 256), 256, 0, stream>>>(dinv_gr, 1.f, N_GRAPH);
    k_deg_graph<<<cdiv(E_GRAPH, 256), 256, 0, stream>>>(graph_ei + E_GRAPH, dinv_gr, E_GRAPH);
    k_deg_bi<<<cdiv(E, 256), 256, 0, stream>>>(bi_s, bi_g, bi_w, dinv_s, dinv_g, E);
    k_to_dinv<<<cdiv(N_SURF, 256), 256, 0, stream>>>(dinv_s, N_SURF);
    k_to_dinv<<<cdiv(N_GRAPH, 256), 256, 0, stream>>>(dinv_g, N_GRAPH);
    k_to_dinv<<<cdiv(N_GRAPH, 256), 256, 0, stream>>>(dinv_gr, N_GRAPH);
    k_prep_graph<<<cdiv(E_GRAPH, 256), 256, 0, stream>>>(graph_ei, dinv_gr, norm_gr, E_GRAPH);
    k_prep_bi<<<cdiv(E, 256), 256, 0, stream>>>(bi_s, bi_g, bi_w, dinv_s, dinv_g,
                                                bg32, norm_gs, norm_sg, E);

    const int gS = cdiv(N_SURF, 64);   // 469
    const int gG = cdiv(N_GRAPH, 64);  // 188

    for (int i = 0; i < 4; ++i) {
        // ---- diffusion
        k_fill<<<cdiv(128 * 64, 256), 256, 0, stream>>>(spec, 0.f, 128 * 64);
        k_spec<<<240, 256, 0, stream>>>(evecs, mass, dx, spec);
        k_bscale<<<32, 256, 0, stream>>>(spec, evals, diff_time + i * 64, Bsc);
        k_gemm64<128, false><<<gS, 256, 0, stream>>>(evecs, Bsc, xd, N_SURF);
        // ---- MLP (in-place residual on dx)
        k_mlp<<<938, 256, 0, stream>>>(dx, xd, mlp_w0 + i * 8192, mlp_b0 + i * 64,
                                       mlp_w1 + i * 4096, mlp_b1 + i * 64,
                                       mlp_w2 + i * 4096, mlp_b2 + i * 64, N_SURF);
        // ---- graph GCN conv 1
        k_gemm64<64, false><<<gG, 256, 0, stream>>>(gx, gcn_w1 + i * 4096, hg, N_GRAPH);
        k_conv_init64<<<cdiv(N_GRAPH * 64, 256), 256, 0, stream>>>(tmpg, hg, dinv_gr, gcn_b1 + i * 64, N_GRAPH);
        k_scatter<<<cdiv(E_GRAPH, 4), 256, 0, stream>>>(graph_ei, graph_ei + E_GRAPH, norm_gr, hg, tmpg, E_GRAPH, 0, 0);
        // ---- graph GCN conv 2 (relu on input)
        k_gemm64<64, true><<<gG, 256, 0, stream>>>(tmpg, gcn_w2 + i * 4096, hg, N_GRAPH);
        k_conv_init64<<<cdiv(N_GRAPH * 64, 256), 256, 0, stream>>>(gx2, hg, dinv_gr, gcn_b2 + i * 64, N_GRAPH);
        k_scatter<<<cdiv(E_GRAPH, 4), 256, 0, stream>>>(graph_ei, graph_ei + E_GRAPH, norm_gr, hg, gx2, E_GRAPH, 0, 0);

        if (i < 3) {
            // ---- gs conv (graph -> surf), dst sorted
            k_gemm64<64, false><<<gS, 256, 0, stream>>>(dx, gs_w + i * 4096, hs, N_SURF);
            k_gemm64<64, false><<<gG, 256, 0, stream>>>(gx2, gs_w + i * 4096, hg, N_GRAPH);
            k_conv_init64<<<cdiv(N_SURF * 64, 256), 256, 0, stream>>>(nsx, hs, dinv_s, gs_b + i * 64, N_SURF);
            k_scatter_run<<<cdiv(cdiv(E, 32) * 64, 256), 256, 0, stream>>>(bg32, bi_s, norm_gs, hg, nsx, E);
            // ---- sg conv (surf -> graph), dst unsorted
            k_gemm64<64, false><<<gS, 256, 0, stream>>>(dx, sg_w + i * 4096, hs, N_SURF);
            k_gemm64<64, false><<<gG, 256, 0, stream>>>(gx2, sg_w + i * 4096, hg, N_GRAPH);
            k_conv_init64<<<cdiv(N_GRAPH * 64, 256), 256, 0, stream>>>(gx, hg, dinv_g, sg_b + i * 64, N_GRAPH);
            k_scatter<<<cdiv(E, 4), 256, 0, stream>>>(bi_s, bi_g, norm_sg, hs, gx, E, 0, N_SURF);
            // swap surf buffers; gx already holds new graph features
            float* t = dx; dx = nsx; nsx = t;
        } else {
            float* hs1 = hs;
            float* hg1 = hs + N_SURF;
            // ---- gs conv -> out[0:N_SURF]
            k_gemv64<<<cdiv(N_SURF, 4), 256, 0, stream>>>(dx, gs_w_last, hs1, N_SURF);
            k_gemv64<<<cdiv(N_GRAPH, 4), 256, 0, stream>>>(gx2, gs_w_last, hg1, N_GRAPH);
            k_conv_init1<<<cdiv(N_SURF, 256), 256, 0, stream>>>(out, hs1, dinv_s, gs_b_last, N_SURF);
            k_scatter_run1<<<cdiv(cdiv(E, 32), 256), 256, 0, stream>>>(bg32, bi_s, norm_gs, hg1, out, E);
            // ---- sg conv -> out[N_SURF:]
            k_gemv64<<<cdiv(N_SURF, 4), 256, 0, stream>>>(dx, sg_w_last, hs1, N_SURF);
            k_gemv64<<<cdiv(N_GRAPH, 4), 256, 0, stream>>>(gx2, sg_w_last, hg1, N_GRAPH);
            k_conv_init1<<<cdiv(N_GRAPH, 256), 256, 0, stream>>>(out + N_SURF, hg1, dinv_g, sg_b_last, N_GRAPH);
            k_scatter1<<<cdiv(E, 256), 256, 0, stream>>>(bi_s, bg32, norm_sg, hs1, out + N_SURF, E);
        }
    }
}

// Round 12
// 2094.022 us; speedup vs baseline: 1.2194x; 1.2194x over previous
//
#include <hip/hip_runtime.h>

#define N_SURF 30000
#define N_GRAPH 12000
#define K_EIG 128
#define HID 64
#define E_GRAPH 192000

static inline int cdiv(int a, int b) { return (a + b - 1) / b; }

// ---------------------------------------------------------------- small utils
__global__ void k_fill(float* __restrict__ p, float v, int n) {
    int t = blockIdx.x * blockDim.x + threadIdx.x;
    if (t < n) p[t] = v;
}

__global__ void k_filli(int* __restrict__ p, int v, int n) {
    int t = blockIdx.x * blockDim.x + threadIdx.x;
    if (t < n) p[t] = v;
}

__global__ void k_to_dinv(float* __restrict__ p, int n) {
    int t = blockIdx.x * blockDim.x + threadIdx.x;
    if (t < n) p[t] = 1.0f / sqrtf(p[t]);
}

// deg accumulation (indices arrive as int32 from the harness)
__global__ void k_deg_graph(const int* __restrict__ gdst, float* __restrict__ deg, int E) {
    int t = blockIdx.x * blockDim.x + threadIdx.x;
    if (t < E) atomicAdd(&deg[gdst[t]], 1.0f);
}

__global__ void k_deg_bi(const int* __restrict__ bs, const int* __restrict__ bg,
                         const float* __restrict__ w, float* __restrict__ deg_s,
                         float* __restrict__ deg_g, int E) {
    int t = blockIdx.x * blockDim.x + threadIdx.x;
    if (t < E) {
        float wv = w[t];
        atomicAdd(&deg_s[bs[t]], wv);
        atomicAdd(&deg_g[bg[t] - N_SURF], wv);
    }
}

// ---------------------------------------------------------------- CSR build
__global__ void k_hist_bi(const int* __restrict__ bs, const int* __restrict__ bg,
                          int* __restrict__ cnt_s, int* __restrict__ cnt_g, int E) {
    int t = blockIdx.x * blockDim.x + threadIdx.x;
    if (t < E) {
        atomicAdd(&cnt_s[bs[t]], 1);
        atomicAdd(&cnt_g[bg[t] - N_SURF], 1);
    }
}

__global__ void k_hist_gr(const int* __restrict__ gdst, int* __restrict__ cnt, int E) {
    int t = blockIdx.x * blockDim.x + threadIdx.x;
    if (t < E) atomicAdd(&cnt[gdst[t]], 1);
}

// one-block exclusive scan: rowptr[i] = sum_{j<i} cnt[j]; rowptr[n] = total (n <= ~32k)
__global__ __launch_bounds__(256) void k_scan(const int* __restrict__ cnt,
                                              int* __restrict__ rowptr, int n) {
    __shared__ int part[256];
    int per = (n + 255) / 256;
    int lo = threadIdx.x * per, hi = min(lo + per, n);
    int s = 0;
    for (int i = lo; i < hi; ++i) s += cnt[i];
    part[threadIdx.x] = s;
    __syncthreads();
    for (int off = 1; off < 256; off <<= 1) {
        int v = (threadIdx.x >= off) ? part[threadIdx.x - off] : 0;
        __syncthreads();
        part[threadIdx.x] += v;
        __syncthreads();
    }
    int base = (threadIdx.x == 0) ? 0 : part[threadIdx.x - 1];
    for (int i = lo; i < hi; ++i) { rowptr[i] = base; base += cnt[i]; }
    if (threadIdx.x == 0) rowptr[n] = part[255];
}

// fill both bipartite CSRs; norms computed inline (self dinv of src side is 1)
__global__ void k_fill_csr_bi(const int* __restrict__ bs, const int* __restrict__ bg,
                              const float* __restrict__ w, const float* __restrict__ dinv_s,
                              const float* __restrict__ dinv_g,
                              const int* __restrict__ rp_s, int* __restrict__ cur_s,
                              int* __restrict__ csr_s_src, float* __restrict__ csr_s_nrm,
                              const int* __restrict__ rp_g, int* __restrict__ cur_g,
                              int* __restrict__ csr_g_src, float* __restrict__ csr_g_nrm,
                              int E) {
    int t = blockIdx.x * blockDim.x + threadIdx.x;
    if (t >= E) return;
    int s = bs[t], g = bg[t] - N_SURF;
    float wv = w[t];
    // row = surf (gs conv): src is graph node, norm = dinv_s[s] * w
    int ps = rp_s[s] + atomicAdd(&cur_s[s], 1);
    csr_s_src[ps] = g;
    csr_s_nrm[ps] = dinv_s[s] * wv;
    // row = graph (sg conv): src is surf node, norm = dinv_g[g] * w
    int pg = rp_g[g] + atomicAdd(&cur_g[g], 1);
    csr_g_src[pg] = s;
    csr_g_nrm[pg] = dinv_g[g] * wv;
}

__global__ void k_fill_csr_gr(const int* __restrict__ ei, const float* __restrict__ dinv,
                              const int* __restrict__ rp, int* __restrict__ cur,
                              int* __restrict__ csr_src, float* __restrict__ csr_nrm, int E) {
    int t = blockIdx.x * blockDim.x + threadIdx.x;
    if (t >= E) return;
    int s = ei[t], d = ei[E + t];
    int p = rp[d] + atomicAdd(&cur[d], 1);
    csr_src[p] = s;
    csr_nrm[p] = dinv[s] * dinv[d];
}

// ---------------------------------------------------------------- input linears
__global__ void k_lin(const float* __restrict__ X, const float* __restrict__ W,
                      const float* __restrict__ b, float* __restrict__ out, int M, int K) {
    int t = blockIdx.x * blockDim.x + threadIdx.x;
    if (t >= M * HID) return;
    int r = t >> 6, h = t & 63;
    float acc = b[h];
    for (int k = 0; k < K; ++k) acc = fmaf(X[r * K + k], W[k * HID + h], acc);
    out[t] = acc;
}

// ---------------------------------------------------------------- spec = evecs^T @ (mass * dx)
__global__ __launch_bounds__(256) void k_spec(const float* __restrict__ evecs,
                                              const float* __restrict__ mass,
                                              const float* __restrict__ dx,
                                              float* __restrict__ spec) {
    __shared__ float evs[32 * 128];
    __shared__ float xms[32 * 64];
    const int h = threadIdx.x & 63, eg = threadIdx.x >> 6;
    float acc[32];
#pragma unroll
    for (int i = 0; i < 32; ++i) acc[i] = 0.f;
    for (int r0 = blockIdx.x * 32; r0 < N_SURF; r0 += gridDim.x * 32) {
        __syncthreads();
        for (int idx = threadIdx.x; idx < 32 * 128; idx += 256) {
            int rr = idx >> 7, k = idx & 127;
            int row = r0 + rr;
            evs[idx] = (row < N_SURF) ? evecs[(size_t)row * 128 + k] : 0.f;
        }
        for (int idx = threadIdx.x; idx < 32 * 64; idx += 256) {
            int rr = idx >> 6, c = idx & 63;
            int row = r0 + rr;
            xms[idx] = (row < N_SURF) ? mass[row] * dx[(size_t)row * 64 + c] : 0.f;
        }
        __syncthreads();
        for (int rr = 0; rr < 32; ++rr) {
            float xv = xms[rr * 64 + h];
            const float* ep = &evs[rr * 128 + eg * 32];
#pragma unroll
            for (int e = 0; e < 32; ++e) acc[e] = fmaf(ep[e], xv, acc[e]);
        }
    }
#pragma unroll
    for (int e = 0; e < 32; ++e) atomicAdd(&spec[(eg * 32 + e) * 64 + h], acc[e]);
}

// Bs[k][h] = exp(-evals[k] * max(t[h],1e-8)) * spec[k][h]
__global__ void k_bscale(const float* __restrict__ spec, const float* __restrict__ evals,
                         const float* __restrict__ t, float* __restrict__ Bs) {
    int idx = blockIdx.x * blockDim.x + threadIdx.x;
    if (idx >= 128 * 64) return;
    int k = idx >> 6, h = idx & 63;
    float tt = fmaxf(t[h], 1e-8f);
    Bs[idx] = expf(-evals[k] * tt) * spec[idx];
}

// ---------------------------------------------------------------- generic GEMM C[M x 64] = op(A[M x K]) @ B[K x 64]
template <int K, bool RELU_A>
__global__ __launch_bounds__(256) void k_gemm64(const float* __restrict__ A,
                                                const float* __restrict__ B,
                                                float* __restrict__ C, int M) {
    __shared__ float Bs[K * 64];
    __shared__ float As[64 * K];
    for (int idx = threadIdx.x; idx < K * 64; idx += 256) Bs[idx] = B[idx];
    const int h = threadIdx.x & 63, rg = threadIdx.x >> 6;
    for (int r0 = blockIdx.x * 64; r0 < M; r0 += gridDim.x * 64) {
        __syncthreads();
        for (int idx = threadIdx.x; idx < 64 * K; idx += 256) {
            int rr = idx / K, k = idx - rr * K;
            int row = r0 + rr;
            float v = (row < M) ? A[(size_t)row * K + k] : 0.f;
            if (RELU_A) v = fmaxf(v, 0.f);
            As[idx] = v;
        }
        __syncthreads();
        float acc[16];
#pragma unroll
        for (int i = 0; i < 16; ++i) acc[i] = 0.f;
        for (int k = 0; k < K; k += 4) {
            float b0 = Bs[(k + 0) * 64 + h], b1 = Bs[(k + 1) * 64 + h];
            float b2 = Bs[(k + 2) * 64 + h], b3 = Bs[(k + 3) * 64 + h];
#pragma unroll
            for (int i = 0; i < 16; ++i) {
                const float* ap = &As[(rg * 16 + i) * K + k];
                acc[i] = fmaf(ap[0], b0, fmaf(ap[1], b1, fmaf(ap[2], b2, fmaf(ap[3], b3, acc[i]))));
            }
        }
#pragma unroll
        for (int i = 0; i < 16; ++i) {
            int row = r0 + rg * 16 + i;
            if (row < M) C[(size_t)row * 64 + h] = acc[i];
        }
    }
}

// ---------------------------------------------------------------- fused 3-layer MLP (per-row), in-place residual on dx
__global__ __launch_bounds__(256) void k_mlp(float* __restrict__ dx, const float* __restrict__ xd,
                                             const float* __restrict__ w0, const float* __restrict__ b0,
                                             const float* __restrict__ w1, const float* __restrict__ b1,
                                             const float* __restrict__ w2, const float* __restrict__ b2,
                                             int M) {
    __shared__ float w0s[128 * 64];
    __shared__ float w1s[64 * 64];
    __shared__ float w2s[64 * 64];
    __shared__ float bsh[3][64];
    __shared__ float feat[4][128];
    __shared__ float h1s[4][64];
    __shared__ float h2s[4][64];
    for (int idx = threadIdx.x; idx < 8192; idx += 256) w0s[idx] = w0[idx];
    for (int idx = threadIdx.x; idx < 4096; idx += 256) { w1s[idx] = w1[idx]; w2s[idx] = w2[idx]; }
    if (threadIdx.x < 64) {
        bsh[0][threadIdx.x] = b0[threadIdx.x];
        bsh[1][threadIdx.x] = b1[threadIdx.x];
        bsh[2][threadIdx.x] = b2[threadIdx.x];
    }
    const int h = threadIdx.x & 63, rg = threadIdx.x >> 6;
    for (int r0 = blockIdx.x * 4; r0 < M; r0 += gridDim.x * 4) {
        int r = r0 + rg;
        __syncthreads();
        feat[rg][h] = dx[(size_t)r * 64 + h];
        feat[rg][64 + h] = xd[(size_t)r * 64 + h];
        __syncthreads();
        float acc = bsh[0][h];
        for (int k = 0; k < 128; k += 4) {
            const float* fp = &feat[rg][k];
            acc = fmaf(fp[0], w0s[(k + 0) * 64 + h],
                  fmaf(fp[1], w0s[(k + 1) * 64 + h],
                  fmaf(fp[2], w0s[(k + 2) * 64 + h],
                  fmaf(fp[3], w0s[(k + 3) * 64 + h], acc))));
        }
        h1s[rg][h] = fmaxf(acc, 0.f);
        __syncthreads();
        acc = bsh[1][h];
        for (int k = 0; k < 64; k += 4) {
            const float* fp = &h1s[rg][k];
            acc = fmaf(fp[0], w1s[(k + 0) * 64 + h],
                  fmaf(fp[1], w1s[(k + 1) * 64 + h],
                  fmaf(fp[2], w1s[(k + 2) * 64 + h],
                  fmaf(fp[3], w1s[(k + 3) * 64 + h], acc))));
        }
        h2s[rg][h] = fmaxf(acc, 0.f);
        __syncthreads();
        acc = bsh[2][h];
        for (int k = 0; k < 64; k += 4) {
            const float* fp = &h2s[rg][k];
            acc = fmaf(fp[0], w2s[(k + 0) * 64 + h],
                  fmaf(fp[1], w2s[(k + 1) * 64 + h],
                  fmaf(fp[2], w2s[(k + 2) * 64 + h],
                  fmaf(fp[3], w2s[(k + 3) * 64 + h], acc))));
        }
        dx[(size_t)r * 64 + h] += acc;
    }
}

// ---------------------------------------------------------------- fused CSR gather conv:
// out[r][h] = b[h] + dinv[r]^2 * Hself[r][h] + sum_{e in row r} nrm[e] * Hsrc[src[e]][h]
__global__ __launch_bounds__(256) void k_gather64(
    const int* __restrict__ rowptr, const int* __restrict__ csr_src,
    const float* __restrict__ csr_nrm, const float* __restrict__ Hsrc,
    const float* __restrict__ Hself, const float* __restrict__ dinv,
    const float* __restrict__ b, float* __restrict__ out, int M) {
    int r = blockIdx.x * 4 + (threadIdx.x >> 6);
    int h = threadIdx.x & 63;
    if (r >= M) return;
    int e0 = rowptr[r], e1 = rowptr[r + 1];
    float dv = dinv[r];
    float acc = fmaf(dv * dv, Hself[(size_t)r * 64 + h], b[h]);
    int e = e0;
    for (; e + 1 < e1; e += 2) {
        float n0 = csr_nrm[e], n1 = csr_nrm[e + 1];
        int s0 = csr_src[e], s1 = csr_src[e + 1];
        acc = fmaf(n0, Hsrc[(size_t)s0 * 64 + h], acc);
        acc = fmaf(n1, Hsrc[(size_t)s1 * 64 + h], acc);
    }
    if (e < e1) acc = fmaf(csr_nrm[e], Hsrc[(size_t)csr_src[e] * 64 + h], acc);
    out[(size_t)r * 64 + h] = acc;
}

// 1-channel variant (last block): one wave per row, lanes stride edges
__global__ __launch_bounds__(256) void k_gather1(
    const int* __restrict__ rowptr, const int* __restrict__ csr_src,
    const float* __restrict__ csr_nrm, const float* __restrict__ H1src,
    const float* __restrict__ H1self, const float* __restrict__ dinv,
    const float* __restrict__ b, float* __restrict__ out, int M) {
    int r = blockIdx.x * 4 + (threadIdx.x >> 6);
    int l = threadIdx.x & 63;
    if (r >= M) return;
    int e0 = rowptr[r], e1 = rowptr[r + 1];
    float acc = 0.f;
    for (int e = e0 + l; e < e1; e += 64)
        acc = fmaf(csr_nrm[e], H1src[csr_src[e]], acc);
    for (int off = 32; off; off >>= 1) acc += __shfl_down(acc, off, 64);
    if (l == 0) {
        float dv = dinv[r];
        out[r] = fmaf(dv * dv, H1self[r], b[0]) + acc;
    }
}

// ---------------------------------------------------------------- GEMV (last block, HID -> 1)
__global__ void k_gemv64(const float* __restrict__ A, const float* __restrict__ w,
                         float* __restrict__ out, int M) {
    int gid = blockIdx.x * blockDim.x + threadIdx.x;
    int r = gid >> 6, l = gid & 63;
    if (r >= M) return;
    float v = A[(size_t)r * 64 + l] * w[l];
    for (int off = 32; off; off >>= 1) v += __shfl_down(v, off, 64);
    if (l == 0) out[r] = v;
}

// ================================================================ host
extern "C" void kernel_launch(void* const* d_in, const int* in_sizes, int n_in,
                              void* d_out, int out_size, void* d_ws, size_t ws_size,
                              hipStream_t stream) {
    const float* x_surf   = (const float*)d_in[0];
    const float* x_graph  = (const float*)d_in[1];
    const float* mass     = (const float*)d_in[2];
    const float* evals    = (const float*)d_in[3];
    const float* evecs    = (const float*)d_in[4];
    const float* bi_w     = (const float*)d_in[5];
    const float* lin1_w   = (const float*)d_in[6];
    const float* lin1_b   = (const float*)d_in[7];
    const float* lin2_w   = (const float*)d_in[8];
    const float* lin2_b   = (const float*)d_in[9];
    const float* diff_time= (const float*)d_in[10];
    const float* mlp_w0   = (const float*)d_in[11];
    const float* mlp_b0   = (const float*)d_in[12];
    const float* mlp_w1   = (const float*)d_in[13];
    const float* mlp_b1   = (const float*)d_in[14];
    const float* mlp_w2   = (const float*)d_in[15];
    const float* mlp_b2   = (const float*)d_in[16];
    const float* gcn_w1   = (const float*)d_in[17];
    const float* gcn_b1   = (const float*)d_in[18];
    const float* gcn_w2   = (const float*)d_in[19];
    const float* gcn_b2   = (const float*)d_in[20];
    const float* gs_w     = (const float*)d_in[21];
    const float* gs_b     = (const float*)d_in[22];
    const float* gs_w_last= (const float*)d_in[23];
    const float* gs_b_last= (const float*)d_in[24];
    const float* sg_w     = (const float*)d_in[25];
    const float* sg_b     = (const float*)d_in[26];
    const float* sg_w_last= (const float*)d_in[27];
    const float* sg_b_last= (const float*)d_in[28];
    const int* graph_ei   = (const int*)d_in[29];   // int32 from harness
    const int* bi_s       = (const int*)d_in[30];   // int32, values [0, N_SURF)
    const int* bi_g       = (const int*)d_in[31];   // int32, values [N_SURF, N_SURF+N_GRAPH)
    const int E = in_sizes[5];
    float* out = (float*)d_out;

    // ---- workspace carve (floats/ints) — ~75 MB at E≈1.1M
    float* p = (float*)d_ws;
    float* surfA = p; p += (size_t)N_SURF * 64;
    float* surfB = p; p += (size_t)N_SURF * 64;
    float* xd    = p; p += (size_t)N_SURF * 64;
    float* hs    = p; p += (size_t)N_SURF * 64;
    float* gA    = p; p += (size_t)N_GRAPH * 64;
    float* gB    = p; p += (size_t)N_GRAPH * 64;
    float* tmpg  = p; p += (size_t)N_GRAPH * 64;
    float* hg    = p; p += (size_t)N_GRAPH * 64;
    float* spec  = p; p += 128 * 64;
    float* Bsc   = p; p += 128 * 64;
    float* dinv_s  = p; p += N_SURF;
    float* dinv_g  = p; p += N_GRAPH;
    float* dinv_gr = p; p += N_GRAPH;
    // CSR structures
    int* cnt_s = (int*)p; p += N_SURF;      // histogram, then reused as cursor
    int* cnt_g = (int*)p; p += N_GRAPH;
    int* cnt_gr= (int*)p; p += N_GRAPH;
    int* rp_s  = (int*)p; p += N_SURF + 1;
    int* rp_g  = (int*)p; p += N_GRAPH + 1;
    int* rp_gr = (int*)p; p += N_GRAPH + 1;
    int*   csr_s_src = (int*)p;   p += E;
    float* csr_s_nrm = p;         p += E;
    int*   csr_g_src = (int*)p;   p += E;
    float* csr_g_nrm = p;         p += E;
    int*   csr_gr_src= (int*)p;   p += E_GRAPH;
    float* csr_gr_nrm= p;         p += E_GRAPH;

    float* dx  = surfA;
    float* nsx = surfB;
    float* gx  = gA;
    float* gx2 = gB;

    // ---- setup: input linears, degrees, CSR build
    k_lin<<<cdiv(N_SURF * 64, 256), 256, 0, stream>>>(x_surf, lin1_w, lin1_b, dx, N_SURF, 5);
    k_lin<<<cdiv(N_GRAPH * 64, 256), 256, 0, stream>>>(x_graph, lin2_w, lin2_b, gx, N_GRAPH, 20);
    k_fill<<<cdiv(N_SURF, 256), 256, 0, stream>>>(dinv_s, 1.f, N_SURF);
    k_fill<<<cdiv(N_GRAPH, 256), 256, 0, stream>>>(dinv_g, 1.f, N_GRAPH);
    k_fill<<<cdiv(N_GRAPH, 256), 256, 0, stream>>>(dinv_gr, 1.f, N_GRAPH);
    k_deg_graph<<<cdiv(E_GRAPH, 256), 256, 0, stream>>>(graph_ei + E_GRAPH, dinv_gr, E_GRAPH);
    k_deg_bi<<<cdiv(E, 256), 256, 0, stream>>>(bi_s, bi_g, bi_w, dinv_s, dinv_g, E);
    k_to_dinv<<<cdiv(N_SURF, 256), 256, 0, stream>>>(dinv_s, N_SURF);
    k_to_dinv<<<cdiv(N_GRAPH, 256), 256, 0, stream>>>(dinv_g, N_GRAPH);
    k_to_dinv<<<cdiv(N_GRAPH, 256), 256, 0, stream>>>(dinv_gr, N_GRAPH);
    // histograms
    k_filli<<<cdiv(N_SURF, 256), 256, 0, stream>>>(cnt_s, 0, N_SURF);
    k_filli<<<cdiv(N_GRAPH, 256), 256, 0, stream>>>(cnt_g, 0, N_GRAPH);
    k_filli<<<cdiv(N_GRAPH, 256), 256, 0, stream>>>(cnt_gr, 0, N_GRAPH);
    k_hist_bi<<<cdiv(E, 256), 256, 0, stream>>>(bi_s, bi_g, cnt_s, cnt_g, E);
    k_hist_gr<<<cdiv(E_GRAPH, 256), 256, 0, stream>>>(graph_ei + E_GRAPH, cnt_gr, E_GRAPH);
    // scans
    k_scan<<<1, 256, 0, stream>>>(cnt_s, rp_s, N_SURF);
    k_scan<<<1, 256, 0, stream>>>(cnt_g, rp_g, N_GRAPH);
    k_scan<<<1, 256, 0, stream>>>(cnt_gr, rp_gr, N_GRAPH);
    // reset counters -> cursors, then fill CSRs (norms computed inline)
    k_filli<<<cdiv(N_SURF, 256), 256, 0, stream>>>(cnt_s, 0, N_SURF);
    k_filli<<<cdiv(N_GRAPH, 256), 256, 0, stream>>>(cnt_g, 0, N_GRAPH);
    k_filli<<<cdiv(N_GRAPH, 256), 256, 0, stream>>>(cnt_gr, 0, N_GRAPH);
    k_fill_csr_bi<<<cdiv(E, 256), 256, 0, stream>>>(bi_s, bi_g, bi_w, dinv_s, dinv_g,
                                                    rp_s, cnt_s, csr_s_src, csr_s_nrm,
                                                    rp_g, cnt_g, csr_g_src, csr_g_nrm, E);
    k_fill_csr_gr<<<cdiv(E_GRAPH, 256), 256, 0, stream>>>(graph_ei, dinv_gr, rp_gr, cnt_gr,
                                                          csr_gr_src, csr_gr_nrm, E_GRAPH);

    const int gS = cdiv(N_SURF, 64);   // 469
    const int gG = cdiv(N_GRAPH, 64);  // 188

    for (int i = 0; i < 4; ++i) {
        // ---- diffusion
        k_fill<<<cdiv(128 * 64, 256), 256, 0, stream>>>(spec, 0.f, 128 * 64);
        k_spec<<<240, 256, 0, stream>>>(evecs, mass, dx, spec);
        k_bscale<<<32, 256, 0, stream>>>(spec, evals, diff_time + i * 64, Bsc);
        k_gemm64<128, false><<<gS, 256, 0, stream>>>(evecs, Bsc, xd, N_SURF);
        // ---- MLP (in-place residual on dx)
        k_mlp<<<938, 256, 0, stream>>>(dx, xd, mlp_w0 + i * 8192, mlp_b0 + i * 64,
                                       mlp_w1 + i * 4096, mlp_b1 + i * 64,
                                       mlp_w2 + i * 4096, mlp_b2 + i * 64, N_SURF);
        // ---- graph GCN conv 1 (gather, fused conv-init)
        k_gemm64<64, false><<<gG, 256, 0, stream>>>(gx, gcn_w1 + i * 4096, hg, N_GRAPH);
        k_gather64<<<cdiv(N_GRAPH, 4), 256, 0, stream>>>(rp_gr, csr_gr_src, csr_gr_nrm,
                                                         hg, hg, dinv_gr, gcn_b1 + i * 64,
                                                         tmpg, N_GRAPH);
        // ---- graph GCN conv 2 (relu on input)
        k_gemm64<64, true><<<gG, 256, 0, stream>>>(tmpg, gcn_w2 + i * 4096, hg, N_GRAPH);
        k_gather64<<<cdiv(N_GRAPH, 4), 256, 0, stream>>>(rp_gr, csr_gr_src, csr_gr_nrm,
                                                         hg, hg, dinv_gr, gcn_b2 + i * 64,
                                                         gx2, N_GRAPH);

        if (i < 3) {
            // ---- gs conv (graph -> surf): out_surf = b + dinv_s^2*Hs + sum norm_gs*Hg
            k_gemm64<64, false><<<gS, 256, 0, stream>>>(dx, gs_w + i * 4096, hs, N_SURF);
            k_gemm64<64, false><<<gG, 256, 0, stream>>>(gx2, gs_w + i * 4096, hg, N_GRAPH);
            k_gather64<<<cdiv(N_SURF, 4), 256, 0, stream>>>(rp_s, csr_s_src, csr_s_nrm,
                                                            hg, hs, dinv_s, gs_b + i * 64,
                                                            nsx, N_SURF);
            // ---- sg conv (surf -> graph): out_graph = b + dinv_g^2*Hg + sum norm_sg*Hs
            k_gemm64<64, false><<<gS, 256, 0, stream>>>(dx, sg_w + i * 4096, hs, N_SURF);
            k_gemm64<64, false><<<gG, 256, 0, stream>>>(gx2, sg_w + i * 4096, hg, N_GRAPH);
            k_gather64<<<cdiv(N_GRAPH, 4), 256, 0, stream>>>(rp_g, csr_g_src, csr_g_nrm,
                                                             hs, hg, dinv_g, sg_b + i * 64,
                                                             gx, N_GRAPH);
            // swap surf buffers; gx already holds new graph features
            float* t = dx; dx = nsx; nsx = t;
        } else {
            float* hs1 = hs;
            float* hg1 = hs + N_SURF;
            // ---- gs conv -> out[0:N_SURF]
            k_gemv64<<<cdiv(N_SURF, 4), 256, 0, stream>>>(dx, gs_w_last, hs1, N_SURF);
            k_gemv64<<<cdiv(N_GRAPH, 4), 256, 0, stream>>>(gx2, gs_w_last, hg1, N_GRAPH);
            k_gather1<<<cdiv(N_SURF, 4), 256, 0, stream>>>(rp_s, csr_s_src, csr_s_nrm,
                                                           hg1, hs1, dinv_s, gs_b_last,
                                                           out, N_SURF);
            // ---- sg conv -> out[N_SURF:]
            k_gemv64<<<cdiv(N_SURF, 4), 256, 0, stream>>>(dx, sg_w_last, hs1, N_SURF);
            k_gemv64<<<cdiv(N_GRAPH, 4), 256, 0, stream>>>(gx2, sg_w_last, hg1, N_GRAPH);
            k_gather1<<<cdiv(N_GRAPH, 4), 256, 0, stream>>>(rp_g, csr_g_src, csr_g_nrm,
                                                            hs1, hg1, dinv_g, sg_b_last,
                                                            out + N_SURF, N_GRAPH);
        }
    }
}

// Round 13
// 1827.329 us; speedup vs baseline: 1.3973x; 1.1459x over previous
//
#include <hip/hip_runtime.h>

#define N_SURF 30000
#define N_GRAPH 12000
#define K_EIG 128
#define HID 64
#define E_GRAPH 192000
#define NPART 240

static inline int cdiv(int a, int b) { return (a + b - 1) / b; }

// ---------------------------------------------------------------- small utils
__global__ void k_fill(float* __restrict__ p, float v, int n) {
    int t = blockIdx.x * blockDim.x + threadIdx.x;
    if (t < n) p[t] = v;
}

__global__ void k_filli(int* __restrict__ p, int v, int n) {
    int t = blockIdx.x * blockDim.x + threadIdx.x;
    if (t < n) p[t] = v;
}

__global__ void k_to_dinv(float* __restrict__ p, int n) {
    int t = blockIdx.x * blockDim.x + threadIdx.x;
    if (t < n) p[t] = 1.0f / sqrtf(p[t]);
}

// fused degree + histogram (one pass over bipartite edges)
__global__ void k_deg_hist_bi(const int* __restrict__ bs, const int* __restrict__ bg,
                              const float* __restrict__ w, float* __restrict__ deg_s,
                              float* __restrict__ deg_g, int* __restrict__ cnt_s,
                              int* __restrict__ cnt_g, int E) {
    int t = blockIdx.x * blockDim.x + threadIdx.x;
    if (t < E) {
        int s = bs[t], g = bg[t] - N_SURF;
        float wv = w[t];
        atomicAdd(&deg_s[s], wv);
        atomicAdd(&deg_g[g], wv);
        atomicAdd(&cnt_s[s], 1);
        atomicAdd(&cnt_g[g], 1);
    }
}

__global__ void k_deg_hist_gr(const int* __restrict__ gdst, float* __restrict__ deg,
                              int* __restrict__ cnt, int E) {
    int t = blockIdx.x * blockDim.x + threadIdx.x;
    if (t < E) {
        int d = gdst[t];
        atomicAdd(&deg[d], 1.0f);
        atomicAdd(&cnt[d], 1);
    }
}

// one-block exclusive scan: rowptr[i] = sum_{j<i} cnt[j]; rowptr[n] = total
__global__ __launch_bounds__(256) void k_scan(const int* __restrict__ cnt,
                                              int* __restrict__ rowptr, int n) {
    __shared__ int part[256];
    int per = (n + 255) / 256;
    int lo = threadIdx.x * per, hi = min(lo + per, n);
    int s = 0;
    for (int i = lo; i < hi; ++i) s += cnt[i];
    part[threadIdx.x] = s;
    __syncthreads();
    for (int off = 1; off < 256; off <<= 1) {
        int v = (threadIdx.x >= off) ? part[threadIdx.x - off] : 0;
        __syncthreads();
        part[threadIdx.x] += v;
        __syncthreads();
    }
    int base = (threadIdx.x == 0) ? 0 : part[threadIdx.x - 1];
    for (int i = lo; i < hi; ++i) { rowptr[i] = base; base += cnt[i]; }
    if (threadIdx.x == 0) rowptr[n] = part[255];
}

// bi_surf is sorted -> surf-rowed CSR is the identity layout: sequential writes, no cursors
__global__ void k_fill_csr_s_seq(const int* __restrict__ bs, const int* __restrict__ bg,
                                 const float* __restrict__ w, const float* __restrict__ dinv_s,
                                 int2* __restrict__ csr, int E) {
    int t = blockIdx.x * blockDim.x + threadIdx.x;
    if (t >= E) return;
    int s = bs[t], g = bg[t] - N_SURF;
    csr[t] = make_int2(g, __float_as_int(dinv_s[s] * w[t]));
}

// graph-rowed CSR: cursor scatter (packed 8B per edge)
__global__ void k_fill_csr_g(const int* __restrict__ bs, const int* __restrict__ bg,
                             const float* __restrict__ w, const float* __restrict__ dinv_g,
                             const int* __restrict__ rp, int* __restrict__ cur,
                             int2* __restrict__ csr, int E) {
    int t = blockIdx.x * blockDim.x + threadIdx.x;
    if (t >= E) return;
    int s = bs[t], g = bg[t] - N_SURF;
    int pp = rp[g] + atomicAdd(&cur[g], 1);
    csr[pp] = make_int2(s, __float_as_int(dinv_g[g] * w[t]));
}

__global__ void k_fill_csr_gr(const int* __restrict__ ei, const float* __restrict__ dinv,
                              const int* __restrict__ rp, int* __restrict__ cur,
                              int2* __restrict__ csr, int E) {
    int t = blockIdx.x * blockDim.x + threadIdx.x;
    if (t >= E) return;
    int s = ei[t], d = ei[E + t];
    int pp = rp[d] + atomicAdd(&cur[d], 1);
    csr[pp] = make_int2(s, __float_as_int(dinv[s] * dinv[d]));
}

// ---------------------------------------------------------------- input linears
__global__ void k_lin(const float* __restrict__ X, const float* __restrict__ W,
                      const float* __restrict__ b, float* __restrict__ out, int M, int K) {
    int t = blockIdx.x * blockDim.x + threadIdx.x;
    if (t >= M * HID) return;
    int r = t >> 6, h = t & 63;
    float acc = b[h];
    for (int k = 0; k < K; ++k) acc = fmaf(X[r * K + k], W[k * HID + h], acc);
    out[t] = acc;
}

// ---------------------------------------------------------------- spec stage 1: partial sums (no atomics)
__global__ __launch_bounds__(256) void k_spec_part(const float* __restrict__ evecs,
                                                   const float* __restrict__ mass,
                                                   const float* __restrict__ dx,
                                                   float* __restrict__ partial) {
    __shared__ float evs[32 * 128];
    __shared__ float xms[32 * 64];
    const int h = threadIdx.x & 63, eg = threadIdx.x >> 6;
    float acc[32];
#pragma unroll
    for (int i = 0; i < 32; ++i) acc[i] = 0.f;
    for (int r0 = blockIdx.x * 32; r0 < N_SURF; r0 += gridDim.x * 32) {
        __syncthreads();
        for (int idx = threadIdx.x; idx < 32 * 128; idx += 256) {
            int rr = idx >> 7, k = idx & 127;
            int row = r0 + rr;
            evs[idx] = (row < N_SURF) ? evecs[(size_t)row * 128 + k] : 0.f;
        }
        for (int idx = threadIdx.x; idx < 32 * 64; idx += 256) {
            int rr = idx >> 6, c = idx & 63;
            int row = r0 + rr;
            xms[idx] = (row < N_SURF) ? mass[row] * dx[(size_t)row * 64 + c] : 0.f;
        }
        __syncthreads();
        for (int rr = 0; rr < 32; ++rr) {
            float xv = xms[rr * 64 + h];
            const float* ep = &evs[rr * 128 + eg * 32];
#pragma unroll
            for (int e = 0; e < 32; ++e) acc[e] = fmaf(ep[e], xv, acc[e]);
        }
    }
    float* outp = &partial[(size_t)blockIdx.x * 8192];
#pragma unroll
    for (int e = 0; e < 32; ++e) outp[(eg * 32 + e) * 64 + h] = acc[e];
}

// spec stage 2 + bscale fused: Bsc[k][h] = exp(-evals[k]*max(t[h],1e-8)) * sum_b partial[b][k][h]
__global__ void k_spec_reduce_bscale(const float* __restrict__ partial,
                                     const float* __restrict__ evals,
                                     const float* __restrict__ t,
                                     float* __restrict__ Bsc) {
    int idx = blockIdx.x * blockDim.x + threadIdx.x;
    if (idx >= 128 * 64) return;
    int k = idx >> 6, h = idx & 63;
    float s = 0.f;
    for (int b = 0; b < NPART; ++b) s += partial[(size_t)b * 8192 + idx];
    float tt = fmaxf(t[h], 1e-8f);
    Bsc[idx] = expf(-evals[k] * tt) * s;
}

// ---------------------------------------------------------------- GEMM C[M x 64] = op(concat(A1,A2)[M x K]) @ B[K x 64]
// rows < M1 read A1, rows >= M1 read A2[(row-M1)]
template <int K, bool RELU_A>
__global__ __launch_bounds__(256) void k_gemm64(const float* __restrict__ A1,
                                                const float* __restrict__ A2, int M1,
                                                const float* __restrict__ B,
                                                float* __restrict__ C, int M) {
    __shared__ float Bs[K * 64];
    __shared__ float As[64 * K];
    for (int idx = threadIdx.x; idx < K * 64; idx += 256) Bs[idx] = B[idx];
    const int h = threadIdx.x & 63, rg = threadIdx.x >> 6;
    for (int r0 = blockIdx.x * 64; r0 < M; r0 += gridDim.x * 64) {
        __syncthreads();
        for (int idx = threadIdx.x; idx < 64 * K; idx += 256) {
            int rr = idx / K, k = idx - rr * K;
            int row = r0 + rr;
            float v = 0.f;
            if (row < M) {
                v = (row < M1) ? A1[(size_t)row * K + k]
                               : A2[(size_t)(row - M1) * K + k];
                if (RELU_A) v = fmaxf(v, 0.f);
            }
            As[idx] = v;
        }
        __syncthreads();
        float acc[16];
#pragma unroll
        for (int i = 0; i < 16; ++i) acc[i] = 0.f;
        for (int k = 0; k < K; k += 4) {
            float b0 = Bs[(k + 0) * 64 + h], b1 = Bs[(k + 1) * 64 + h];
            float b2 = Bs[(k + 2) * 64 + h], b3 = Bs[(k + 3) * 64 + h];
#pragma unroll
            for (int i = 0; i < 16; ++i) {
                const float* ap = &As[(rg * 16 + i) * K + k];
                acc[i] = fmaf(ap[0], b0, fmaf(ap[1], b1, fmaf(ap[2], b2, fmaf(ap[3], b3, acc[i]))));
            }
        }
#pragma unroll
        for (int i = 0; i < 16; ++i) {
            int row = r0 + rg * 16 + i;
            if (row < M) C[(size_t)row * 64 + h] = acc[i];
        }
    }
}

// evecs GEMM, K=128, 32-row tiles (48 KB LDS -> 3 blocks/CU)
__global__ __launch_bounds__(256) void k_gemm128_r32(const float* __restrict__ A,
                                                     const float* __restrict__ B,
                                                     float* __restrict__ C, int M) {
    __shared__ float Bs[128 * 64];
    __shared__ float As[32 * 128];
    for (int idx = threadIdx.x; idx < 128 * 64; idx += 256) Bs[idx] = B[idx];
    const int h = threadIdx.x & 63, rg = threadIdx.x >> 6;
    for (int r0 = blockIdx.x * 32; r0 < M; r0 += gridDim.x * 32) {
        __syncthreads();
        for (int idx = threadIdx.x; idx < 32 * 128; idx += 256) {
            int rr = idx >> 7, k = idx & 127;
            int row = r0 + rr;
            As[idx] = (row < M) ? A[(size_t)row * 128 + k] : 0.f;
        }
        __syncthreads();
        float acc[8];
#pragma unroll
        for (int i = 0; i < 8; ++i) acc[i] = 0.f;
        for (int k = 0; k < 128; k += 4) {
            float b0 = Bs[(k + 0) * 64 + h], b1 = Bs[(k + 1) * 64 + h];
            float b2 = Bs[(k + 2) * 64 + h], b3 = Bs[(k + 3) * 64 + h];
#pragma unroll
            for (int i = 0; i < 8; ++i) {
                const float* ap = &As[(rg * 8 + i) * 128 + k];
                acc[i] = fmaf(ap[0], b0, fmaf(ap[1], b1, fmaf(ap[2], b2, fmaf(ap[3], b3, acc[i]))));
            }
        }
#pragma unroll
        for (int i = 0; i < 8; ++i) {
            int row = r0 + rg * 8 + i;
            if (row < M) C[(size_t)row * 64 + h] = acc[i];
        }
    }
}

// ---------------------------------------------------------------- fused 3-layer MLP (per-row), in-place residual on dx
__global__ __launch_bounds__(256) void k_mlp(float* __restrict__ dx, const float* __restrict__ xd,
                                             const float* __restrict__ w0, const float* __restrict__ b0,
                                             const float* __restrict__ w1, const float* __restrict__ b1,
                                             const float* __restrict__ w2, const float* __restrict__ b2,
                                             int M) {
    __shared__ float w0s[128 * 64];
    __shared__ float w1s[64 * 64];
    __shared__ float w2s[64 * 64];
    __shared__ float bsh[3][64];
    __shared__ float feat[4][128];
    __shared__ float h1s[4][64];
    __shared__ float h2s[4][64];
    for (int idx = threadIdx.x; idx < 8192; idx += 256) w0s[idx] = w0[idx];
    for (int idx = threadIdx.x; idx < 4096; idx += 256) { w1s[idx] = w1[idx]; w2s[idx] = w2[idx]; }
    if (threadIdx.x < 64) {
        bsh[0][threadIdx.x] = b0[threadIdx.x];
        bsh[1][threadIdx.x] = b1[threadIdx.x];
        bsh[2][threadIdx.x] = b2[threadIdx.x];
    }
    const int h = threadIdx.x & 63, rg = threadIdx.x >> 6;
    for (int r0 = blockIdx.x * 4; r0 < M; r0 += gridDim.x * 4) {
        int r = r0 + rg;
        __syncthreads();
        feat[rg][h] = dx[(size_t)r * 64 + h];
        feat[rg][64 + h] = xd[(size_t)r * 64 + h];
        __syncthreads();
        float acc = bsh[0][h];
        for (int k = 0; k < 128; k += 4) {
            const float* fp = &feat[rg][k];
            acc = fmaf(fp[0], w0s[(k + 0) * 64 + h],
                  fmaf(fp[1], w0s[(k + 1) * 64 + h],
                  fmaf(fp[2], w0s[(k + 2) * 64 + h],
                  fmaf(fp[3], w0s[(k + 3) * 64 + h], acc))));
        }
        h1s[rg][h] = fmaxf(acc, 0.f);
        __syncthreads();
        acc = bsh[1][h];
        for (int k = 0; k < 64; k += 4) {
            const float* fp = &h1s[rg][k];
            acc = fmaf(fp[0], w1s[(k + 0) * 64 + h],
                  fmaf(fp[1], w1s[(k + 1) * 64 + h],
                  fmaf(fp[2], w1s[(k + 2) * 64 + h],
                  fmaf(fp[3], w1s[(k + 3) * 64 + h], acc))));
        }
        h2s[rg][h] = fmaxf(acc, 0.f);
        __syncthreads();
        acc = bsh[2][h];
        for (int k = 0; k < 64; k += 4) {
            const float* fp = &h2s[rg][k];
            acc = fmaf(fp[0], w2s[(k + 0) * 64 + h],
                  fmaf(fp[1], w2s[(k + 1) * 64 + h],
                  fmaf(fp[2], w2s[(k + 2) * 64 + h],
                  fmaf(fp[3], w2s[(k + 3) * 64 + h], acc))));
        }
        dx[(size_t)r * 64 + h] += acc;
    }
}

// ---------------------------------------------------------------- fused CSR gather conv (int2 edges):
// out[r][h] = b[h] + dinv[r]^2 * Hself[r][h] + sum_e nrm[e] * Hsrc[src[e]][h]
__global__ __launch_bounds__(256) void k_gather64(
    const int* __restrict__ rowptr, const int2* __restrict__ csr,
    const float* __restrict__ Hsrc, const float* __restrict__ Hself,
    const float* __restrict__ dinv, const float* __restrict__ b,
    float* __restrict__ out, int M) {
    int r = blockIdx.x * 4 + (threadIdx.x >> 6);
    int h = threadIdx.x & 63;
    if (r >= M) return;
    int e0 = rowptr[r], e1 = rowptr[r + 1];
    float dv = dinv[r];
    float acc = fmaf(dv * dv, Hself[(size_t)r * 64 + h], b[h]);
    int e = e0;
    for (; e + 1 < e1; e += 2) {
        int2 c0 = csr[e], c1 = csr[e + 1];
        acc = fmaf(__int_as_float(c0.y), Hsrc[(size_t)c0.x * 64 + h], acc);
        acc = fmaf(__int_as_float(c1.y), Hsrc[(size_t)c1.x * 64 + h], acc);
    }
    if (e < e1) {
        int2 c = csr[e];
        acc = fmaf(__int_as_float(c.y), Hsrc[(size_t)c.x * 64 + h], acc);
    }
    out[(size_t)r * 64 + h] = acc;
}

// 1-channel variant (last block): one wave per row, lanes stride edges
__global__ __launch_bounds__(256) void k_gather1(
    const int* __restrict__ rowptr, const int2* __restrict__ csr,
    const float* __restrict__ H1src, const float* __restrict__ H1self,
    const float* __restrict__ dinv, const float* __restrict__ b,
    float* __restrict__ out, int M) {
    int r = blockIdx.x * 4 + (threadIdx.x >> 6);
    int l = threadIdx.x & 63;
    if (r >= M) return;
    int e0 = rowptr[r], e1 = rowptr[r + 1];
    float acc = 0.f;
    for (int e = e0 + l; e < e1; e += 64) {
        int2 c = csr[e];
        acc = fmaf(__int_as_float(c.y), H1src[c.x], acc);
    }
    for (int off = 32; off; off >>= 1) acc += __shfl_down(acc, off, 64);
    if (l == 0) {
        float dv = dinv[r];
        out[r] = fmaf(dv * dv, H1self[r], b[0]) + acc;
    }
}

// ---------------------------------------------------------------- concat GEMV (last block, HID -> 1)
__global__ void k_gemv64c(const float* __restrict__ A1, const float* __restrict__ A2, int M1,
                          const float* __restrict__ w, float* __restrict__ out, int M) {
    int gid = blockIdx.x * blockDim.x + threadIdx.x;
    int r = gid >> 6, l = gid & 63;
    if (r >= M) return;
    const float* row = (r < M1) ? &A1[(size_t)r * 64] : &A2[(size_t)(r - M1) * 64];
    float v = row[l] * w[l];
    for (int off = 32; off; off >>= 1) v += __shfl_down(v, off, 64);
    if (l == 0) out[r] = v;
}

// ================================================================ host
extern "C" void kernel_launch(void* const* d_in, const int* in_sizes, int n_in,
                              void* d_out, int out_size, void* d_ws, size_t ws_size,
                              hipStream_t stream) {
    const float* x_surf   = (const float*)d_in[0];
    const float* x_graph  = (const float*)d_in[1];
    const float* mass     = (const float*)d_in[2];
    const float* evals    = (const float*)d_in[3];
    const float* evecs    = (const float*)d_in[4];
    const float* bi_w     = (const float*)d_in[5];
    const float* lin1_w   = (const float*)d_in[6];
    const float* lin1_b   = (const float*)d_in[7];
    const float* lin2_w   = (const float*)d_in[8];
    const float* lin2_b   = (const float*)d_in[9];
    const float* diff_time= (const float*)d_in[10];
    const float* mlp_w0   = (const float*)d_in[11];
    const float* mlp_b0   = (const float*)d_in[12];
    const float* mlp_w1   = (const float*)d_in[13];
    const float* mlp_b1   = (const float*)d_in[14];
    const float* mlp_w2   = (const float*)d_in[15];
    const float* mlp_b2   = (const float*)d_in[16];
    const float* gcn_w1   = (const float*)d_in[17];
    const float* gcn_b1   = (const float*)d_in[18];
    const float* gcn_w2   = (const float*)d_in[19];
    const float* gcn_b2   = (const float*)d_in[20];
    const float* gs_w     = (const float*)d_in[21];
    const float* gs_b     = (const float*)d_in[22];
    const float* gs_w_last= (const float*)d_in[23];
    const float* gs_b_last= (const float*)d_in[24];
    const float* sg_w     = (const float*)d_in[25];
    const float* sg_b     = (const float*)d_in[26];
    const float* sg_w_last= (const float*)d_in[27];
    const float* sg_b_last= (const float*)d_in[28];
    const int* graph_ei   = (const int*)d_in[29];
    const int* bi_s       = (const int*)d_in[30];
    const int* bi_g       = (const int*)d_in[31];
    const int E = in_sizes[5];
    float* out = (float*)d_out;

    // ---- workspace carve
    float* p = (float*)d_ws;
    float* surfA = p; p += (size_t)N_SURF * 64;
    float* surfB = p; p += (size_t)N_SURF * 64;
    float* xd    = p; p += (size_t)N_SURF * 64;
    float* hcat  = p; p += (size_t)(N_SURF + N_GRAPH) * 64;  // concat surf||graph
    float* gA    = p; p += (size_t)N_GRAPH * 64;
    float* gB    = p; p += (size_t)N_GRAPH * 64;
    float* tmpg  = p; p += (size_t)N_GRAPH * 64;
    float* hg    = p; p += (size_t)N_GRAPH * 64;
    float* partial = p; p += (size_t)NPART * 8192;
    float* Bsc   = p; p += 128 * 64;
    float* dinv_s  = p; p += N_SURF;
    float* dinv_g  = p; p += N_GRAPH;
    float* dinv_gr = p; p += N_GRAPH;
    int* cnt_s = (int*)p; p += N_SURF;
    int* cnt_g = (int*)p; p += N_GRAPH;
    int* cnt_gr= (int*)p; p += N_GRAPH;
    int* rp_s  = (int*)p; p += N_SURF + 1;
    int* rp_g  = (int*)p; p += N_GRAPH + 1;
    int* rp_gr = (int*)p; p += N_GRAPH + 1;
    p += ((size_t)p & 4) ? 1 : 0;  // 8B align for int2
    int2* csr_s  = (int2*)p; p += 2 * (size_t)E;
    int2* csr_g  = (int2*)p; p += 2 * (size_t)E;
    int2* csr_gr = (int2*)p; p += 2 * (size_t)E_GRAPH;

    float* hg_part = hcat + (size_t)N_SURF * 64;
    float* dx  = surfA;
    float* nsx = surfB;
    float* gx  = gA;
    float* gx2 = gB;

    // ---- setup: input linears, degrees+histograms (fused), CSR build
    k_lin<<<cdiv(N_SURF * 64, 256), 256, 0, stream>>>(x_surf, lin1_w, lin1_b, dx, N_SURF, 5);
    k_lin<<<cdiv(N_GRAPH * 64, 256), 256, 0, stream>>>(x_graph, lin2_w, lin2_b, gx, N_GRAPH, 20);
    k_fill<<<cdiv(N_SURF, 256), 256, 0, stream>>>(dinv_s, 1.f, N_SURF);
    k_fill<<<cdiv(N_GRAPH, 256), 256, 0, stream>>>(dinv_g, 1.f, N_GRAPH);
    k_fill<<<cdiv(N_GRAPH, 256), 256, 0, stream>>>(dinv_gr, 1.f, N_GRAPH);
    k_filli<<<cdiv(N_SURF, 256), 256, 0, stream>>>(cnt_s, 0, N_SURF);
    k_filli<<<cdiv(N_GRAPH, 256), 256, 0, stream>>>(cnt_g, 0, N_GRAPH);
    k_filli<<<cdiv(N_GRAPH, 256), 256, 0, stream>>>(cnt_gr, 0, N_GRAPH);
    k_deg_hist_bi<<<cdiv(E, 256), 256, 0, stream>>>(bi_s, bi_g, bi_w, dinv_s, dinv_g,
                                                    cnt_s, cnt_g, E);
    k_deg_hist_gr<<<cdiv(E_GRAPH, 256), 256, 0, stream>>>(graph_ei + E_GRAPH, dinv_gr, cnt_gr, E_GRAPH);
    k_to_dinv<<<cdiv(N_SURF, 256), 256, 0, stream>>>(dinv_s, N_SURF);
    k_to_dinv<<<cdiv(N_GRAPH, 256), 256, 0, stream>>>(dinv_g, N_GRAPH);
    k_to_dinv<<<cdiv(N_GRAPH, 256), 256, 0, stream>>>(dinv_gr, N_GRAPH);
    k_scan<<<1, 256, 0, stream>>>(cnt_s, rp_s, N_SURF);
    k_scan<<<1, 256, 0, stream>>>(cnt_g, rp_g, N_GRAPH);
    k_scan<<<1, 256, 0, stream>>>(cnt_gr, rp_gr, N_GRAPH);
    // surf CSR: identity layout (bi_surf sorted), sequential writes
    k_fill_csr_s_seq<<<cdiv(E, 256), 256, 0, stream>>>(bi_s, bi_g, bi_w, dinv_s, csr_s, E);
    // graph-rowed CSRs: cursor scatter
    k_filli<<<cdiv(N_GRAPH, 256), 256, 0, stream>>>(cnt_g, 0, N_GRAPH);
    k_filli<<<cdiv(N_GRAPH, 256), 256, 0, stream>>>(cnt_gr, 0, N_GRAPH);
    k_fill_csr_g<<<cdiv(E, 256), 256, 0, stream>>>(bi_s, bi_g, bi_w, dinv_g, rp_g, cnt_g, csr_g, E);
    k_fill_csr_gr<<<cdiv(E_GRAPH, 256), 256, 0, stream>>>(graph_ei, dinv_gr, rp_gr, cnt_gr,
                                                          csr_gr, E_GRAPH);

    const int gG = cdiv(N_GRAPH, 64);        // 188
    const int gC = cdiv(N_SURF + N_GRAPH, 64); // 657

    for (int i = 0; i < 4; ++i) {
        // ---- diffusion: two-stage spec + fused bscale, then evecs gemm
        k_spec_part<<<NPART, 256, 0, stream>>>(evecs, mass, dx, partial);
        k_spec_reduce_bscale<<<32, 256, 0, stream>>>(partial, evals, diff_time + i * 64, Bsc);
        k_gemm128_r32<<<938, 256, 0, stream>>>(evecs, Bsc, xd, N_SURF);
        // ---- MLP (in-place residual on dx)
        k_mlp<<<938, 256, 0, stream>>>(dx, xd, mlp_w0 + i * 8192, mlp_b0 + i * 64,
                                       mlp_w1 + i * 4096, mlp_b1 + i * 64,
                                       mlp_w2 + i * 4096, mlp_b2 + i * 64, N_SURF);
        // ---- graph GCN conv 1 (gather, fused conv-init)
        k_gemm64<64, false><<<gG, 256, 0, stream>>>(gx, gx, N_GRAPH, gcn_w1 + i * 4096, hg, N_GRAPH);
        k_gather64<<<cdiv(N_GRAPH, 4), 256, 0, stream>>>(rp_gr, csr_gr, hg, hg, dinv_gr,
                                                         gcn_b1 + i * 64, tmpg, N_GRAPH);
        // ---- graph GCN conv 2 (relu on input)
        k_gemm64<64, true><<<gG, 256, 0, stream>>>(tmpg, tmpg, N_GRAPH, gcn_w2 + i * 4096, hg, N_GRAPH);
        k_gather64<<<cdiv(N_GRAPH, 4), 256, 0, stream>>>(rp_gr, csr_gr, hg, hg, dinv_gr,
                                                         gcn_b2 + i * 64, gx2, N_GRAPH);

        if (i < 3) {
            // ---- gs conv (graph -> surf): hcat = concat(dx,gx2) @ gs_w
            k_gemm64<64, false><<<gC, 256, 0, stream>>>(dx, gx2, N_SURF, gs_w + i * 4096,
                                                        hcat, N_SURF + N_GRAPH);
            k_gather64<<<cdiv(N_SURF, 4), 256, 0, stream>>>(rp_s, csr_s, hg_part, hcat, dinv_s,
                                                            gs_b + i * 64, nsx, N_SURF);
            // ---- sg conv (surf -> graph): hcat = concat(dx,gx2) @ sg_w
            k_gemm64<64, false><<<gC, 256, 0, stream>>>(dx, gx2, N_SURF, sg_w + i * 4096,
                                                        hcat, N_SURF + N_GRAPH);
            k_gather64<<<cdiv(N_GRAPH, 4), 256, 0, stream>>>(rp_g, csr_g, hcat, hg_part, dinv_g,
                                                             sg_b + i * 64, gx, N_GRAPH);
            // swap surf buffers; gx already holds new graph features
            float* t = dx; dx = nsx; nsx = t;
        } else {
            float* h1 = hcat;                    // 42000 scalars
            float* h1g = hcat + N_SURF;
            // ---- gs conv -> out[0:N_SURF]
            k_gemv64c<<<cdiv((N_SURF + N_GRAPH) * 64, 256), 256, 0, stream>>>(
                dx, gx2, N_SURF, gs_w_last, h1, N_SURF + N_GRAPH);
            k_gather1<<<cdiv(N_SURF, 4), 256, 0, stream>>>(rp_s, csr_s, h1g, h1, dinv_s,
                                                           gs_b_last, out, N_SURF);
            // ---- sg conv -> out[N_SURF:]
            k_gemv64c<<<cdiv((N_SURF + N_GRAPH) * 64, 256), 256, 0, stream>>>(
                dx, gx2, N_SURF, sg_w_last, h1, N_SURF + N_GRAPH);
            k_gather1<<<cdiv(N_GRAPH, 4), 256, 0, stream>>>(rp_g, csr_g, h1, h1g, dinv_g,
                                                            sg_b_last, out + N_SURF, N_GRAPH);
        }
    }
}

// Round 14
// 1724.251 us; speedup vs baseline: 1.4809x; 1.0598x over previous
//
#include <hip/hip_runtime.h>

#define N_SURF 30000
#define N_GRAPH 12000
#define K_EIG 128
#define HID 64
#define E_GRAPH 192000
#define NPART 240

static inline int cdiv(int a, int b) { return (a + b - 1) / b; }

// ---------------------------------------------------------------- small utils
__global__ void k_fill(float* __restrict__ p, float v, int n) {
    int t = blockIdx.x * blockDim.x + threadIdx.x;
    if (t < n) p[t] = v;
}

__global__ void k_filli(int* __restrict__ p, int v, int n) {
    int t = blockIdx.x * blockDim.x + threadIdx.x;
    if (t < n) p[t] = v;
}

// rp_s directly from sorted bi_surf (no histogram, no scan, no atomics)
__global__ void k_rp_sorted(const int* __restrict__ bs, int* __restrict__ rp, int E) {
    int t = blockIdx.x * blockDim.x + threadIdx.x;
    if (t >= E) return;
    if (t == 0) {
        int b0 = bs[0];
        for (int s = 0; s <= b0; ++s) rp[s] = 0;
        int bl = bs[E - 1];
        for (int s = bl + 1; s <= N_SURF; ++s) rp[s] = E;
    } else {
        int a = bs[t - 1], b = bs[t];
        for (int s = a + 1; s <= b; ++s) rp[s] = t;
    }
}

// dinv_s[r] = rsqrt(1 + sum of w over r's run) — segment sum, no atomics
__global__ void k_dinv_s_seg(const int* __restrict__ rp, const float* __restrict__ w,
                             float* __restrict__ dinv_s, int M) {
    int r = blockIdx.x * blockDim.x + threadIdx.x;
    if (r >= M) return;
    int e0 = rp[r], e1 = rp[r + 1];
    float s = 1.0f;
    for (int e = e0; e < e1; ++e) s += w[e];
    dinv_s[r] = rsqrtf(s);
}

// LDS-privatized int histogram over 12000 bins (launch with ~32 blocks)
__global__ __launch_bounds__(256) void k_hist_cnt_g(const int* __restrict__ idx, int off,
                                                    int* __restrict__ cnt, int E) {
    __shared__ int hc[N_GRAPH];
    for (int i = threadIdx.x; i < N_GRAPH; i += 256) hc[i] = 0;
    __syncthreads();
    for (int t = blockIdx.x * 256 + threadIdx.x; t < E; t += gridDim.x * 256)
        atomicAdd(&hc[idx[t] - off], 1);
    __syncthreads();
    for (int i = threadIdx.x; i < N_GRAPH; i += 256) {
        int v = hc[i];
        if (v) atomicAdd(&cnt[i], v);
    }
}

// LDS-privatized float histogram (weighted degree)
__global__ __launch_bounds__(256) void k_hist_w_g(const int* __restrict__ bg,
                                                  const float* __restrict__ w,
                                                  float* __restrict__ deg, int E) {
    __shared__ float hw[N_GRAPH];
    for (int i = threadIdx.x; i < N_GRAPH; i += 256) hw[i] = 0.f;
    __syncthreads();
    for (int t = blockIdx.x * 256 + threadIdx.x; t < E; t += gridDim.x * 256)
        atomicAdd(&hw[bg[t] - N_SURF], w[t]);
    __syncthreads();
    for (int i = threadIdx.x; i < N_GRAPH; i += 256) {
        float v = hw[i];
        if (v != 0.f) atomicAdd(&deg[i], v);
    }
}

// dinv_g = rsqrt(1+deg_w); dinv_gr = rsqrt(1+cnt_gr) — one pass
__global__ void k_dinv_g_both(const float* __restrict__ deg_w, const int* __restrict__ cnt_gr,
                              float* __restrict__ dinv_g, float* __restrict__ dinv_gr, int n) {
    int t = blockIdx.x * blockDim.x + threadIdx.x;
    if (t < n) {
        dinv_g[t] = rsqrtf(1.0f + deg_w[t]);
        dinv_gr[t] = rsqrtf(1.0f + (float)cnt_gr[t]);
    }
}

// one-block exclusive scan: rowptr[i] = sum_{j<i} cnt[j]; rowptr[n] = total
__global__ __launch_bounds__(256) void k_scan(const int* __restrict__ cnt,
                                              int* __restrict__ rowptr, int n) {
    __shared__ int part[256];
    int per = (n + 255) / 256;
    int lo = threadIdx.x * per, hi = min(lo + per, n);
    int s = 0;
    for (int i = lo; i < hi; ++i) s += cnt[i];
    part[threadIdx.x] = s;
    __syncthreads();
    for (int off = 1; off < 256; off <<= 1) {
        int v = (threadIdx.x >= off) ? part[threadIdx.x - off] : 0;
        __syncthreads();
        part[threadIdx.x] += v;
        __syncthreads();
    }
    int base = (threadIdx.x == 0) ? 0 : part[threadIdx.x - 1];
    for (int i = lo; i < hi; ++i) { rowptr[i] = base; base += cnt[i]; }
    if (threadIdx.x == 0) rowptr[n] = part[255];
}

// surf CSR: identity layout (bi_surf sorted), pure sequential writes
__global__ void k_fill_csr_s_seq(const int* __restrict__ bs, const int* __restrict__ bg,
                                 const float* __restrict__ w, const float* __restrict__ dinv_s,
                                 int2* __restrict__ csr, int E) {
    int t = blockIdx.x * blockDim.x + threadIdx.x;
    if (t >= E) return;
    csr[t] = make_int2(bg[t] - N_SURF, __float_as_int(dinv_s[bs[t]] * w[t]));
}

// graph-rowed CSR: cursor scatter (packed 8B per edge)
__global__ void k_fill_csr_g(const int* __restrict__ bs, const int* __restrict__ bg,
                             const float* __restrict__ w, const float* __restrict__ dinv_g,
                             const int* __restrict__ rp, int* __restrict__ cur,
                             int2* __restrict__ csr, int E) {
    int t = blockIdx.x * blockDim.x + threadIdx.x;
    if (t >= E) return;
    int s = bs[t], g = bg[t] - N_SURF;
    int pp = rp[g] + atomicAdd(&cur[g], 1);
    csr[pp] = make_int2(s, __float_as_int(dinv_g[g] * w[t]));
}

__global__ void k_fill_csr_gr(const int* __restrict__ ei, const float* __restrict__ dinv,
                              const int* __restrict__ rp, int* __restrict__ cur,
                              int2* __restrict__ csr, int E) {
    int t = blockIdx.x * blockDim.x + threadIdx.x;
    if (t >= E) return;
    int s = ei[t], d = ei[E + t];
    int pp = rp[d] + atomicAdd(&cur[d], 1);
    csr[pp] = make_int2(s, __float_as_int(dinv[s] * dinv[d]));
}

// ---------------------------------------------------------------- input linears
__global__ void k_lin(const float* __restrict__ X, const float* __restrict__ W,
                      const float* __restrict__ b, float* __restrict__ out, int M, int K) {
    int t = blockIdx.x * blockDim.x + threadIdx.x;
    if (t >= M * HID) return;
    int r = t >> 6, h = t & 63;
    float acc = b[h];
    for (int k = 0; k < K; ++k) acc = fmaf(X[r * K + k], W[k * HID + h], acc);
    out[t] = acc;
}

// ---------------------------------------------------------------- spec stage 1: partial sums (no atomics)
__global__ __launch_bounds__(256) void k_spec_part(const float* __restrict__ evecs,
                                                   const float* __restrict__ mass,
                                                   const float* __restrict__ dx,
                                                   float* __restrict__ partial) {
    __shared__ float evs[32 * 128];
    __shared__ float xms[32 * 64];
    const int h = threadIdx.x & 63, eg = threadIdx.x >> 6;
    float acc[32];
#pragma unroll
    for (int i = 0; i < 32; ++i) acc[i] = 0.f;
    for (int r0 = blockIdx.x * 32; r0 < N_SURF; r0 += gridDim.x * 32) {
        __syncthreads();
        for (int idx = threadIdx.x; idx < 32 * 128; idx += 256) {
            int rr = idx >> 7, k = idx & 127;
            int row = r0 + rr;
            evs[idx] = (row < N_SURF) ? evecs[(size_t)row * 128 + k] : 0.f;
        }
        for (int idx = threadIdx.x; idx < 32 * 64; idx += 256) {
            int rr = idx >> 6, c = idx & 63;
            int row = r0 + rr;
            xms[idx] = (row < N_SURF) ? mass[row] * dx[(size_t)row * 64 + c] : 0.f;
        }
        __syncthreads();
        for (int rr = 0; rr < 32; ++rr) {
            float xv = xms[rr * 64 + h];
            const float* ep = &evs[rr * 128 + eg * 32];
#pragma unroll
            for (int e = 0; e < 32; ++e) acc[e] = fmaf(ep[e], xv, acc[e]);
        }
    }
    float* outp = &partial[(size_t)blockIdx.x * 8192];
#pragma unroll
    for (int e = 0; e < 32; ++e) outp[(eg * 32 + e) * 64 + h] = acc[e];
}

// spec stage 2 + bscale fused
__global__ void k_spec_reduce_bscale(const float* __restrict__ partial,
                                     const float* __restrict__ evals,
                                     const float* __restrict__ t,
                                     float* __restrict__ Bsc) {
    int idx = blockIdx.x * blockDim.x + threadIdx.x;
    if (idx >= 128 * 64) return;
    int k = idx >> 6, h = idx & 63;
    float s = 0.f;
    for (int b = 0; b < NPART; ++b) s += partial[(size_t)b * 8192 + idx];
    float tt = fmaxf(t[h], 1e-8f);
    Bsc[idx] = expf(-evals[k] * tt) * s;
}

// ---------------------------------------------------------------- GEMM K=64, concat A, single B
template <bool RELU_A>
__global__ __launch_bounds__(256) void k_gemm64(const float* __restrict__ A1,
                                                const float* __restrict__ A2, int M1,
                                                const float* __restrict__ B,
                                                float* __restrict__ C, int M) {
    __shared__ float Bs[64 * 64];
    __shared__ float As[64 * 64];
    for (int idx = threadIdx.x; idx < 64 * 64; idx += 256) Bs[idx] = B[idx];
    const int h = threadIdx.x & 63, rg = threadIdx.x >> 6;
    for (int r0 = blockIdx.x * 64; r0 < M; r0 += gridDim.x * 64) {
        __syncthreads();
        for (int idx = threadIdx.x; idx < 64 * 64; idx += 256) {
            int rr = idx >> 6, k = idx & 63;
            int row = r0 + rr;
            float v = 0.f;
            if (row < M) {
                v = (row < M1) ? A1[(size_t)row * 64 + k]
                               : A2[(size_t)(row - M1) * 64 + k];
                if (RELU_A) v = fmaxf(v, 0.f);
            }
            As[idx] = v;
        }
        __syncthreads();
        float acc[16];
#pragma unroll
        for (int i = 0; i < 16; ++i) acc[i] = 0.f;
        for (int k = 0; k < 64; k += 4) {
            float b0 = Bs[(k + 0) * 64 + h], b1 = Bs[(k + 1) * 64 + h];
            float b2 = Bs[(k + 2) * 64 + h], b3 = Bs[(k + 3) * 64 + h];
#pragma unroll
            for (int i = 0; i < 16; ++i) {
                const float* ap = &As[(rg * 16 + i) * 64 + k];
                acc[i] = fmaf(ap[0], b0, fmaf(ap[1], b1, fmaf(ap[2], b2, fmaf(ap[3], b3, acc[i]))));
            }
        }
#pragma unroll
        for (int i = 0; i < 16; ++i) {
            int row = r0 + rg * 16 + i;
            if (row < M) C[(size_t)row * 64 + h] = acc[i];
        }
    }
}

// GEMM K=64, concat A, TWO B matrices, two outputs (gs+sg share input)
__global__ __launch_bounds__(256) void k_gemm64_dual(const float* __restrict__ A1,
                                                     const float* __restrict__ A2, int M1,
                                                     const float* __restrict__ Ba,
                                                     const float* __restrict__ Bb,
                                                     float* __restrict__ Ca,
                                                     float* __restrict__ Cb, int M) {
    __shared__ float Bsa[64 * 64];
    __shared__ float Bsb[64 * 64];
    __shared__ float As[64 * 64];
    for (int idx = threadIdx.x; idx < 64 * 64; idx += 256) { Bsa[idx] = Ba[idx]; Bsb[idx] = Bb[idx]; }
    const int h = threadIdx.x & 63, rg = threadIdx.x >> 6;
    for (int r0 = blockIdx.x * 64; r0 < M; r0 += gridDim.x * 64) {
        __syncthreads();
        for (int idx = threadIdx.x; idx < 64 * 64; idx += 256) {
            int rr = idx >> 6, k = idx & 63;
            int row = r0 + rr;
            float v = 0.f;
            if (row < M) {
                v = (row < M1) ? A1[(size_t)row * 64 + k]
                               : A2[(size_t)(row - M1) * 64 + k];
            }
            As[idx] = v;
        }
        __syncthreads();
        float acca[16], accb[16];
#pragma unroll
        for (int i = 0; i < 16; ++i) { acca[i] = 0.f; accb[i] = 0.f; }
        for (int k = 0; k < 64; k += 2) {
            float a0 = Bsa[(k + 0) * 64 + h], a1 = Bsa[(k + 1) * 64 + h];
            float b0 = Bsb[(k + 0) * 64 + h], b1 = Bsb[(k + 1) * 64 + h];
#pragma unroll
            for (int i = 0; i < 16; ++i) {
                const float* ap = &As[(rg * 16 + i) * 64 + k];
                acca[i] = fmaf(ap[0], a0, fmaf(ap[1], a1, acca[i]));
                accb[i] = fmaf(ap[0], b0, fmaf(ap[1], b1, accb[i]));
            }
        }
#pragma unroll
        for (int i = 0; i < 16; ++i) {
            int row = r0 + rg * 16 + i;
            if (row < M) {
                Ca[(size_t)row * 64 + h] = acca[i];
                Cb[(size_t)row * 64 + h] = accb[i];
            }
        }
    }
}

// evecs GEMM, K=128, 32-row tiles
__global__ __launch_bounds__(256) void k_gemm128_r32(const float* __restrict__ A,
                                                     const float* __restrict__ B,
                                                     float* __restrict__ C, int M) {
    __shared__ float Bs[128 * 64];
    __shared__ float As[32 * 128];
    for (int idx = threadIdx.x; idx < 128 * 64; idx += 256) Bs[idx] = B[idx];
    const int h = threadIdx.x & 63, rg = threadIdx.x >> 6;
    for (int r0 = blockIdx.x * 32; r0 < M; r0 += gridDim.x * 32) {
        __syncthreads();
        for (int idx = threadIdx.x; idx < 32 * 128; idx += 256) {
            int rr = idx >> 7, k = idx & 127;
            int row = r0 + rr;
            As[idx] = (row < M) ? A[(size_t)row * 128 + k] : 0.f;
        }
        __syncthreads();
        float acc[8];
#pragma unroll
        for (int i = 0; i < 8; ++i) acc[i] = 0.f;
        for (int k = 0; k < 128; k += 4) {
            float b0 = Bs[(k + 0) * 64 + h], b1 = Bs[(k + 1) * 64 + h];
            float b2 = Bs[(k + 2) * 64 + h], b3 = Bs[(k + 3) * 64 + h];
#pragma unroll
            for (int i = 0; i < 8; ++i) {
                const float* ap = &As[(rg * 8 + i) * 128 + k];
                acc[i] = fmaf(ap[0], b0, fmaf(ap[1], b1, fmaf(ap[2], b2, fmaf(ap[3], b3, acc[i]))));
            }
        }
#pragma unroll
        for (int i = 0; i < 8; ++i) {
            int row = r0 + rg * 8 + i;
            if (row < M) C[(size_t)row * 64 + h] = acc[i];
        }
    }
}

// ---------------------------------------------------------------- fused 3-layer MLP
__global__ __launch_bounds__(256) void k_mlp(float* __restrict__ dx, const float* __restrict__ xd,
                                             const float* __restrict__ w0, const float* __restrict__ b0,
                                             const float* __restrict__ w1, const float* __restrict__ b1,
                                             const float* __restrict__ w2, const float* __restrict__ b2,
                                             int M) {
    __shared__ float w0s[128 * 64];
    __shared__ float w1s[64 * 64];
    __shared__ float w2s[64 * 64];
    __shared__ float bsh[3][64];
    __shared__ float feat[4][128];
    __shared__ float h1s[4][64];
    __shared__ float h2s[4][64];
    for (int idx = threadIdx.x; idx < 8192; idx += 256) w0s[idx] = w0[idx];
    for (int idx = threadIdx.x; idx < 4096; idx += 256) { w1s[idx] = w1[idx]; w2s[idx] = w2[idx]; }
    if (threadIdx.x < 64) {
        bsh[0][threadIdx.x] = b0[threadIdx.x];
        bsh[1][threadIdx.x] = b1[threadIdx.x];
        bsh[2][threadIdx.x] = b2[threadIdx.x];
    }
    const int h = threadIdx.x & 63, rg = threadIdx.x >> 6;
    for (int r0 = blockIdx.x * 4; r0 < M; r0 += gridDim.x * 4) {
        int r = r0 + rg;
        __syncthreads();
        feat[rg][h] = dx[(size_t)r * 64 + h];
        feat[rg][64 + h] = xd[(size_t)r * 64 + h];
        __syncthreads();
        float acc = bsh[0][h];
        for (int k = 0; k < 128; k += 4) {
            const float* fp = &feat[rg][k];
            acc = fmaf(fp[0], w0s[(k + 0) * 64 + h],
                  fmaf(fp[1], w0s[(k + 1) * 64 + h],
                  fmaf(fp[2], w0s[(k + 2) * 64 + h],
                  fmaf(fp[3], w0s[(k + 3) * 64 + h], acc))));
        }
        h1s[rg][h] = fmaxf(acc, 0.f);
        __syncthreads();
        acc = bsh[1][h];
        for (int k = 0; k < 64; k += 4) {
            const float* fp = &h1s[rg][k];
            acc = fmaf(fp[0], w1s[(k + 0) * 64 + h],
                  fmaf(fp[1], w1s[(k + 1) * 64 + h],
                  fmaf(fp[2], w1s[(k + 2) * 64 + h],
                  fmaf(fp[3], w1s[(k + 3) * 64 + h], acc))));
        }
        h2s[rg][h] = fmaxf(acc, 0.f);
        __syncthreads();
        acc = bsh[2][h];
        for (int k = 0; k < 64; k += 4) {
            const float* fp = &h2s[rg][k];
            acc = fmaf(fp[0], w2s[(k + 0) * 64 + h],
                  fmaf(fp[1], w2s[(k + 1) * 64 + h],
                  fmaf(fp[2], w2s[(k + 2) * 64 + h],
                  fmaf(fp[3], w2s[(k + 3) * 64 + h], acc))));
        }
        dx[(size_t)r * 64 + h] += acc;
    }
}

// ---------------------------------------------------------------- CSR gather conv (int2 edges)
__global__ __launch_bounds__(256) void k_gather64(
    const int* __restrict__ rowptr, const int2* __restrict__ csr,
    const float* __restrict__ Hsrc, const float* __restrict__ Hself,
    const float* __restrict__ dinv, const float* __restrict__ b,
    float* __restrict__ out, int M) {
    int r = blockIdx.x * 4 + (threadIdx.x >> 6);
    int h = threadIdx.x & 63;
    if (r >= M) return;
    int e0 = rowptr[r], e1 = rowptr[r + 1];
    float dv = dinv[r];
    float acc = fmaf(dv * dv, Hself[(size_t)r * 64 + h], b[h]);
    int e = e0;
    for (; e + 1 < e1; e += 2) {
        int2 c0 = csr[e], c1 = csr[e + 1];
        acc = fmaf(__int_as_float(c0.y), Hsrc[(size_t)c0.x * 64 + h], acc);
        acc = fmaf(__int_as_float(c1.y), Hsrc[(size_t)c1.x * 64 + h], acc);
    }
    if (e < e1) {
        int2 c = csr[e];
        acc = fmaf(__int_as_float(c.y), Hsrc[(size_t)c.x * 64 + h], acc);
    }
    out[(size_t)r * 64 + h] = acc;
}

// fused bipartite gather: rows [0,N_SURF) do gs conv from hcatA; rows [N_SURF, N_SURF+N_GRAPH) do sg conv from hcatB
__global__ __launch_bounds__(256) void k_gather_bi(
    const int* __restrict__ rp_s, const int2* __restrict__ csr_s, const float* __restrict__ hcatA,
    const int* __restrict__ rp_g, const int2* __restrict__ csr_g, const float* __restrict__ hcatB,
    const float* __restrict__ dinv_s, const float* __restrict__ dinv_g,
    const float* __restrict__ b_gs, const float* __restrict__ b_sg,
    float* __restrict__ out_surf, float* __restrict__ out_graph) {
    int rr = blockIdx.x * 4 + (threadIdx.x >> 6);
    int h = threadIdx.x & 63;
    if (rr < N_SURF) {
        int e0 = rp_s[rr], e1 = rp_s[rr + 1];
        float dv = dinv_s[rr];
        const float* src = hcatA + (size_t)N_SURF * 64;   // graph part
        float acc = fmaf(dv * dv, hcatA[(size_t)rr * 64 + h], b_gs[h]);
        for (int e = e0; e < e1; ++e) {
            int2 c = csr_s[e];
            acc = fmaf(__int_as_float(c.y), src[(size_t)c.x * 64 + h], acc);
        }
        out_surf[(size_t)rr * 64 + h] = acc;
    } else if (rr < N_SURF + N_GRAPH) {
        int r = rr - N_SURF;
        int e0 = rp_g[r], e1 = rp_g[r + 1];
        float dv = dinv_g[r];
        float acc = fmaf(dv * dv, hcatB[(size_t)rr * 64 + h], b_sg[h]);
        for (int e = e0; e < e1; ++e) {
            int2 c = csr_g[e];
            acc = fmaf(__int_as_float(c.y), hcatB[(size_t)c.x * 64 + h], acc);
        }
        out_graph[(size_t)r * 64 + h] = acc;
    }
}

// dual GEMV (last block): one wave per row computes both gs and sg dots
__global__ void k_gemv_dual(const float* __restrict__ A1, const float* __restrict__ A2, int M1,
                            const float* __restrict__ wA, const float* __restrict__ wB,
                            float* __restrict__ oA, float* __restrict__ oB, int M) {
    int gid = blockIdx.x * blockDim.x + threadIdx.x;
    int r = gid >> 6, l = gid & 63;
    if (r >= M) return;
    const float* row = (r < M1) ? &A1[(size_t)r * 64] : &A2[(size_t)(r - M1) * 64];
    float v = row[l];
    float va = v * wA[l], vb = v * wB[l];
    for (int off = 32; off; off >>= 1) {
        va += __shfl_down(va, off, 64);
        vb += __shfl_down(vb, off, 64);
    }
    if (l == 0) { oA[r] = va; oB[r] = vb; }
}

// fused 1-channel bipartite gather (last block): writes the full output vector
__global__ __launch_bounds__(256) void k_gather1_bi(
    const int* __restrict__ rp_s, const int2* __restrict__ csr_s, const float* __restrict__ h1A,
    const int* __restrict__ rp_g, const int2* __restrict__ csr_g, const float* __restrict__ h1B,
    const float* __restrict__ dinv_s, const float* __restrict__ dinv_g,
    const float* __restrict__ b_gs, const float* __restrict__ b_sg,
    float* __restrict__ out) {
    int rr = blockIdx.x * 4 + (threadIdx.x >> 6);
    int l = threadIdx.x & 63;
    if (rr < N_SURF) {
        int e0 = rp_s[rr], e1 = rp_s[rr + 1];
        const float* src = h1A + N_SURF;   // graph part
        float acc = 0.f;
        for (int e = e0 + l; e < e1; e += 64) {
            int2 c = csr_s[e];
            acc = fmaf(__int_as_float(c.y), src[c.x], acc);
        }
        for (int off = 32; off; off >>= 1) acc += __shfl_down(acc, off, 64);
        if (l == 0) {
            float dv = dinv_s[rr];
            out[rr] = fmaf(dv * dv, h1A[rr], b_gs[0]) + acc;
        }
    } else if (rr < N_SURF + N_GRAPH) {
        int r = rr - N_SURF;
        int e0 = rp_g[r], e1 = rp_g[r + 1];
        float acc = 0.f;
        for (int e = e0 + l; e < e1; e += 64) {
            int2 c = csr_g[e];
            acc = fmaf(__int_as_float(c.y), h1B[c.x], acc);
        }
        for (int off = 32; off; off >>= 1) acc += __shfl_down(acc, off, 64);
        if (l == 0) {
            float dv = dinv_g[r];
            out[rr] = fmaf(dv * dv, h1B[rr], b_sg[0]) + acc;
        }
    }
}

// ================================================================ host
extern "C" void kernel_launch(void* const* d_in, const int* in_sizes, int n_in,
                              void* d_out, int out_size, void* d_ws, size_t ws_size,
                              hipStream_t stream) {
    const float* x_surf   = (const float*)d_in[0];
    const float* x_graph  = (const float*)d_in[1];
    const float* mass     = (const float*)d_in[2];
    const float* evals    = (const float*)d_in[3];
    const float* evecs    = (const float*)d_in[4];
    const float* bi_w     = (const float*)d_in[5];
    const float* lin1_w   = (const float*)d_in[6];
    const float* lin1_b   = (const float*)d_in[7];
    const float* lin2_w   = (const float*)d_in[8];
    const float* lin2_b   = (const float*)d_in[9];
    const float* diff_time= (const float*)d_in[10];
    const float* mlp_w0   = (const float*)d_in[11];
    const float* mlp_b0   = (const float*)d_in[12];
    const float* mlp_w1   = (const float*)d_in[13];
    const float* mlp_b1   = (const float*)d_in[14];
    const float* mlp_w2   = (const float*)d_in[15];
    const float* mlp_b2   = (const float*)d_in[16];
    const float* gcn_w1   = (const float*)d_in[17];
    const float* gcn_b1   = (const float*)d_in[18];
    const float* gcn_w2   = (const float*)d_in[19];
    const float* gcn_b2   = (const float*)d_in[20];
    const float* gs_w     = (const float*)d_in[21];
    const float* gs_b     = (const float*)d_in[22];
    const float* gs_w_last= (const float*)d_in[23];
    const float* gs_b_last= (const float*)d_in[24];
    const float* sg_w     = (const float*)d_in[25];
    const float* sg_b     = (const float*)d_in[26];
    const float* sg_w_last= (const float*)d_in[27];
    const float* sg_b_last= (const float*)d_in[28];
    const int* graph_ei   = (const int*)d_in[29];
    const int* bi_s       = (const int*)d_in[30];
    const int* bi_g       = (const int*)d_in[31];
    const int E = in_sizes[5];
    float* out = (float*)d_out;

    // ---- workspace carve
    float* p = (float*)d_ws;
    float* surfA = p; p += (size_t)N_SURF * 64;
    float* surfB = p; p += (size_t)N_SURF * 64;
    float* xd    = p; p += (size_t)N_SURF * 64;
    float* hcatA = p; p += (size_t)(N_SURF + N_GRAPH) * 64;
    float* hcatB = p; p += (size_t)(N_SURF + N_GRAPH) * 64;
    float* gA    = p; p += (size_t)N_GRAPH * 64;
    float* gB    = p; p += (size_t)N_GRAPH * 64;
    float* tmpg  = p; p += (size_t)N_GRAPH * 64;
    float* hg    = p; p += (size_t)N_GRAPH * 64;
    float* partial = p; p += (size_t)NPART * 8192;
    float* Bsc   = p; p += 128 * 64;
    float* dinv_s  = p; p += N_SURF;
    float* dinv_g  = p; p += N_GRAPH;
    float* dinv_gr = p; p += N_GRAPH;
    float* deg_gw  = p; p += N_GRAPH;
    int* cnt_g = (int*)p; p += N_GRAPH;
    int* cnt_gr= (int*)p; p += N_GRAPH;
    int* rp_s  = (int*)p; p += N_SURF + 1;
    int* rp_g  = (int*)p; p += N_GRAPH + 1;
    int* rp_gr = (int*)p; p += N_GRAPH + 1;
    p += ((size_t)p & 4) ? 1 : 0;  // 8B align for int2
    int2* csr_s  = (int2*)p; p += 2 * (size_t)E;
    int2* csr_g  = (int2*)p; p += 2 * (size_t)E;
    int2* csr_gr = (int2*)p; p += 2 * (size_t)E_GRAPH;

    float* dx  = surfA;
    float* nsx = surfB;
    float* gx  = gA;
    float* gx2 = gB;

    // ---- setup
    k_lin<<<cdiv(N_SURF * 64, 256), 256, 0, stream>>>(x_surf, lin1_w, lin1_b, dx, N_SURF, 5);
    k_lin<<<cdiv(N_GRAPH * 64, 256), 256, 0, stream>>>(x_graph, lin2_w, lin2_b, gx, N_GRAPH, 20);
    // surf side: sorted-run rowptr + segment-sum degree (no atomics)
    k_rp_sorted<<<cdiv(E, 256), 256, 0, stream>>>(bi_s, rp_s, E);
    k_dinv_s_seg<<<cdiv(N_SURF, 256), 256, 0, stream>>>(rp_s, bi_w, dinv_s, N_SURF);
    // graph side: LDS-privatized histograms
    k_filli<<<cdiv(N_GRAPH, 256), 256, 0, stream>>>(cnt_g, 0, N_GRAPH);
    k_filli<<<cdiv(N_GRAPH, 256), 256, 0, stream>>>(cnt_gr, 0, N_GRAPH);
    k_fill<<<cdiv(N_GRAPH, 256), 256, 0, stream>>>(deg_gw, 0.f, N_GRAPH);
    k_hist_cnt_g<<<32, 256, 0, stream>>>(bi_g, N_SURF, cnt_g, E);
    k_hist_w_g<<<32, 256, 0, stream>>>(bi_g, bi_w, deg_gw, E);
    k_hist_cnt_g<<<32, 256, 0, stream>>>(graph_ei + E_GRAPH, 0, cnt_gr, E_GRAPH);
    k_scan<<<1, 256, 0, stream>>>(cnt_g, rp_g, N_GRAPH);
    k_scan<<<1, 256, 0, stream>>>(cnt_gr, rp_gr, N_GRAPH);
    k_dinv_g_both<<<cdiv(N_GRAPH, 256), 256, 0, stream>>>(deg_gw, cnt_gr, dinv_g, dinv_gr, N_GRAPH);
    // CSR fills
    k_fill_csr_s_seq<<<cdiv(E, 256), 256, 0, stream>>>(bi_s, bi_g, bi_w, dinv_s, csr_s, E);
    k_filli<<<cdiv(N_GRAPH, 256), 256, 0, stream>>>(cnt_g, 0, N_GRAPH);
    k_filli<<<cdiv(N_GRAPH, 256), 256, 0, stream>>>(cnt_gr, 0, N_GRAPH);
    k_fill_csr_g<<<cdiv(E, 256), 256, 0, stream>>>(bi_s, bi_g, bi_w, dinv_g, rp_g, cnt_g, csr_g, E);
    k_fill_csr_gr<<<cdiv(E_GRAPH, 256), 256, 0, stream>>>(graph_ei, dinv_gr, rp_gr, cnt_gr,
                                                          csr_gr, E_GRAPH);

    const int gG = cdiv(N_GRAPH, 64);          // 188
    const int gC = cdiv(N_SURF + N_GRAPH, 64); // 657

    for (int i = 0; i < 4; ++i) {
        // ---- diffusion
        k_spec_part<<<NPART, 256, 0, stream>>>(evecs, mass, dx, partial);
        k_spec_reduce_bscale<<<32, 256, 0, stream>>>(partial, evals, diff_time + i * 64, Bsc);
        k_gemm128_r32<<<938, 256, 0, stream>>>(evecs, Bsc, xd, N_SURF);
        // ---- MLP (in-place residual on dx)
        k_mlp<<<938, 256, 0, stream>>>(dx, xd, mlp_w0 + i * 8192, mlp_b0 + i * 64,
                                       mlp_w1 + i * 4096, mlp_b1 + i * 64,
                                       mlp_w2 + i * 4096, mlp_b2 + i * 64, N_SURF);
        // ---- graph GCN conv 1
        k_gemm64<false><<<gG, 256, 0, stream>>>(gx, gx, N_GRAPH, gcn_w1 + i * 4096, hg, N_GRAPH);
        k_gather64<<<cdiv(N_GRAPH, 4), 256, 0, stream>>>(rp_gr, csr_gr, hg, hg, dinv_gr,
                                                         gcn_b1 + i * 64, tmpg, N_GRAPH);
        // ---- graph GCN conv 2 (relu on input)
        k_gemm64<true><<<gG, 256, 0, stream>>>(tmpg, tmpg, N_GRAPH, gcn_w2 + i * 4096, hg, N_GRAPH);
        k_gather64<<<cdiv(N_GRAPH, 4), 256, 0, stream>>>(rp_gr, csr_gr, hg, hg, dinv_gr,
                                                         gcn_b2 + i * 64, gx2, N_GRAPH);

        if (i < 3) {
            // ---- gs+sg convs: one dual-B GEMM + one fused gather
            k_gemm64_dual<<<gC, 256, 0, stream>>>(dx, gx2, N_SURF, gs_w + i * 4096,
                                                  sg_w + i * 4096, hcatA, hcatB,
                                                  N_SURF + N_GRAPH);
            k_gather_bi<<<cdiv(N_SURF + N_GRAPH, 4), 256, 0, stream>>>(
                rp_s, csr_s, hcatA, rp_g, csr_g, hcatB, dinv_s, dinv_g,
                gs_b + i * 64, sg_b + i * 64, nsx, gx);
            // swap surf buffers; gx holds new graph features
            float* t = dx; dx = nsx; nsx = t;
        } else {
            float* h1A = hcatA;   // 42000 scalars each
            float* h1B = hcatB;
            k_gemv_dual<<<cdiv((N_SURF + N_GRAPH) * 64, 256), 256, 0, stream>>>(
                dx, gx2, N_SURF, gs_w_last, sg_w_last, h1A, h1B, N_SURF + N_GRAPH);
            k_gather1_bi<<<cdiv(N_SURF + N_GRAPH, 4), 256, 0, stream>>>(
                rp_s, csr_s, h1A, rp_g, csr_g, h1B, dinv_s, dinv_g,
                gs_b_last, sg_b_last, out);
        }
    }
}